// Round 18
// baseline (266.203 us; speedup 1.0000x reference)
//
#include <hip/hip_runtime.h>

typedef unsigned short u16;
typedef float f32x4 __attribute__((ext_vector_type(4)));
typedef float f32x16 __attribute__((ext_vector_type(16)));
typedef __bf16 bf16x8 __attribute__((ext_vector_type(8)));
typedef unsigned int u32x4 __attribute__((ext_vector_type(4)));
typedef u16 u16x4 __attribute__((ext_vector_type(4)));
typedef u16 u16x8 __attribute__((ext_vector_type(8)));

static __device__ __forceinline__ u16 f2bf(float f) {
  union { __bf16 h; u16 u; } c;
  c.h = (__bf16)f;
  return c.u;
}
static __device__ __forceinline__ float bf2f(u16 u) {
  union { unsigned u; float f; } c;
  c.u = ((unsigned)u) << 16;
  return c.f;
}
static __device__ __forceinline__ unsigned cvtpk(float a, float b) {
  unsigned r;
  asm volatile("v_cvt_pk_bf16_f32 %0, %1, %2" : "=v"(r) : "v"(a), "v"(b));
  return r;
}
// after: a = [a.lo31 | b.lo31], b = [a.hi31 | b.hi31]
static __device__ __forceinline__ void plswap(unsigned& a, unsigned& b) {
  asm volatile("v_permlane32_swap_b32 %0, %1" : "+v"(a), "+v"(b));
}

static __device__ __forceinline__ void gload_lds16(const void* g, void* l) {
  __builtin_amdgcn_global_load_lds(
      (const __attribute__((address_space(1))) unsigned int*)g,
      (__attribute__((address_space(3))) unsigned int*)l, 16, 0, 0);
}

// ---------------- fused fp32 -> bf16 convert ----------------
__global__ __launch_bounds__(256) void cvt3_f32_bf16(const float* __restrict__ a,
                                                     const float* __restrict__ bb,
                                                     const float* __restrict__ cc,
                                                     u16* __restrict__ out,
                                                     int n1, int n2, int n3) {
  int i = blockIdx.x * 256 + threadIdx.x;
  const float* src;
  int j = i;
  if (i < n1) { src = a; }
  else if (i < n1 + n2) { src = bb; j = i - n1; }
  else { src = cc; j = i - n1 - n2; if (j >= n3) return; }
  f32x4 v = *((const f32x4*)src + j);
  u16x4 o;
  o[0] = f2bf(v[0]); o[1] = f2bf(v[1]); o[2] = f2bf(v[2]); o[3] = f2bf(v[3]);
  *((u16x4*)out + i) = o;
}

// ---------------- 128x128 GEMM (proven m97-structure) ----------------
template<int OUT_BF16, int FUSE_VT>
__global__ __launch_bounds__(256) void gemm_nt(const u16* __restrict__ A,
                                               const u16* __restrict__ B,
                                               void* __restrict__ Cp,
                                               u16* __restrict__ vt,
                                               int M, int N, int K, int gy) {
  __shared__ __align__(16) u16 lA[128 * 64];
  __shared__ __align__(16) u16 lB[128 * 64];
  const int tid = threadIdx.x;
  const int lane = tid & 63;
  const int wave = tid >> 6;
  const int wm = wave >> 1, wn = wave & 1;
  const int l15 = lane & 15, lg = lane >> 4;

  const int bid = blockIdx.x;
  const int xcd = bid & 7, s = bid >> 3;
  const int pnx = (N >> 7) >> 3;
  const int bm = (s % gy) * 128;
  const int bn = (xcd * pnx + s / gy) * 128;

  f32x4 acc[4][4];
#pragma unroll
  for (int i = 0; i < 4; ++i)
#pragma unroll
    for (int j = 0; j < 4; ++j) acc[i][j] = (f32x4){0.f, 0.f, 0.f, 0.f};

  const u16* Ag[4];
  const u16* Bg[4];
#pragma unroll
  for (int it = 0; it < 4; ++it) {
    const int ss = it * 256 + tid;
    const int row = ss >> 3, g = ss & 7;
    const int gsw = g ^ (row & 7);
    Ag[it] = A + (size_t)(bm + row) * K + gsw * 8;
    Bg[it] = B + (size_t)(bn + row) * K + gsw * 8;
  }

  for (int k0 = 0; k0 < K; k0 += 64) {
#pragma unroll
    for (int it = 0; it < 4; ++it) {
      gload_lds16(Ag[it] + k0, (u16*)lA + (size_t)(it * 256 + tid) * 8);
      gload_lds16(Bg[it] + k0, (u16*)lB + (size_t)(it * 256 + tid) * 8);
    }
    __syncthreads();
#pragma unroll
    for (int kk = 0; kk < 2; ++kk) {
      bf16x8 af[4], bfv[4];
#pragma unroll
      for (int mf = 0; mf < 4; ++mf) {
        const int row = wm * 64 + mf * 16 + l15;
        af[mf] = *(const bf16x8*)((const char*)lA + row * 128 +
                                  ((kk * 64 + lg * 16) ^ ((row & 7) << 4)));
      }
#pragma unroll
      for (int nf = 0; nf < 4; ++nf) {
        const int row = wn * 64 + nf * 16 + l15;
        bfv[nf] = *(const bf16x8*)((const char*)lB + row * 128 +
                                   ((kk * 64 + lg * 16) ^ ((row & 7) << 4)));
      }
#pragma unroll
      for (int mf = 0; mf < 4; ++mf)
#pragma unroll
        for (int nf = 0; nf < 4; ++nf)
          acc[mf][nf] = __builtin_amdgcn_mfma_f32_16x16x32_bf16(af[mf], bfv[nf], acc[mf][nf], 0, 0, 0);
    }
    __syncthreads();
  }

  if (FUSE_VT && bn >= 2048) {
#pragma unroll
    for (int mf = 0; mf < 4; ++mf) {
      const int row0 = bm + wm * 64 + mf * 16 + lg * 4;
      const int b = row0 >> 11, t0 = row0 & 2047;
#pragma unroll
      for (int nf = 0; nf < 4; ++nf) {
        const int colv = bn - 2048 + wn * 64 + nf * 16 + l15;
        const int h = colv >> 6, d = colv & 63;
        u16x4 pk;
        pk[0] = f2bf(acc[mf][nf][0]); pk[1] = f2bf(acc[mf][nf][1]);
        pk[2] = f2bf(acc[mf][nf][2]); pk[3] = f2bf(acc[mf][nf][3]);
        *(u16x4*)&vt[((size_t)((b * 16 + h) * 64 + d)) * 2048 + t0] = pk;
      }
    }
  } else {
#pragma unroll
    for (int mf = 0; mf < 4; ++mf) {
#pragma unroll
      for (int r = 0; r < 4; ++r) {
        const int row = bm + wm * 64 + mf * 16 + lg * 4 + r;
#pragma unroll
        for (int nf = 0; nf < 4; ++nf) {
          const int col = bn + wn * 64 + nf * 16 + l15;
          const float v = acc[mf][nf][r];
          if (OUT_BF16) ((u16*)Cp)[(size_t)row * N + col] = f2bf(v);
          else          ((float*)Cp)[(size_t)row * N + col] = v;
        }
      }
    }
  }
}

// ---------------- flash attention fwd (causal), 32x32 MFMA, 4 waves ----------------
// Block (bh, pi, tr): q-tile pair (pi, 15-pi) of 128 rows; kv-THIRD tr of each
// pass -> 10-12 iters/block, 768 blocks = 3/CU, 12 waves/CU, LDS 32KB.
// Swapped QK^T with mfma_32x32x16 (lane owns q = lane&31); P stays IN REGISTERS
// (cvt_pk_bf16 + permlane32_swap builds the PV B-operand); PV computes O^T so
// rescale/normalize are lane-local. Partial O (l-normalized bf16) + (m,l) out;
// merge3 combines the three kv-thirds.
__global__ __launch_bounds__(256, 3) void attn_fwd(const u16* __restrict__ qkv,
                                                   const u16* __restrict__ vt,
                                                   u16* __restrict__ po0,
                                                   u16* __restrict__ po1,
                                                   u16* __restrict__ po2,
                                                   float* __restrict__ mlf) {
  constexpr int T = 2048, C3 = 3072;
  __shared__ __align__(16) u16 lK[2][64 * 64];
  __shared__ __align__(16) u16 lV[2][64 * 64];
  const int tid = threadIdx.x, lane = tid & 63, w = tid >> 6;  // 4 waves
  const int l31 = lane & 31, h5 = lane >> 5;

  const int bid = blockIdx.x;                 // 768 blocks
  const int xcd = bid & 7, slot = bid >> 3;   // 96 per xcd
  const int bh = xcd * 4 + slot / 24;
  const int rem = slot % 24;
  const int pi = rem / 3, tr = rem % 3;
  const int b = bh >> 4, h = bh & 15;

  const int r0 = tid >> 3, off0 = (tid & 7) * 8;
  const int r1 = r0 + 32;
  const int sb0 = (off0 * 2) ^ ((r0 & 7) << 4);
  const int sb1 = (off0 * 2) ^ ((r1 & 7) << 4);
  const u16* Kbase = qkv + (size_t)b * T * C3 + 1024 + h * 64;
  const u16* Vbase = vt + (size_t)bh * 64 * T;
  u16* pob = (tr == 0) ? po0 : ((tr == 1) ? po1 : po2);

  const float qscale = 0.125f * 1.44269504088896f;  // scale * log2(e)

#pragma unroll 1
  for (int qi = 0; qi < 2; ++qi) {
    const int qt = (qi == 0) ? pi : (15 - pi);
    const int q0 = qt * 128;
    const int n = 2 * qt + 2;
    const int kts = tr * n / 3, kte = (tr + 1) * n / 3;
    const int nit = kte - kts;
    const int qrow = q0 + w * 32 + l31;

    const size_t qoff = ((size_t)b * T + qrow) * C3 + h * 64;
    bf16x8 aq[4];
#pragma unroll
    for (int ks = 0; ks < 4; ++ks)
      aq[ks] = *(const bf16x8*)&qkv[qoff + ks * 16 + h5 * 8];

    float m = -1.0e30f, l = 0.f;
    f32x16 o0, o1;
#pragma unroll
    for (int r = 0; r < 16; ++r) { o0[r] = 0.f; o1[r] = 0.f; }

    if (nit > 0) {
      u32x4 rk0 = *(const u32x4*)(Kbase + (size_t)(kts * 64 + r0) * C3 + off0);
      u32x4 rk1 = *(const u32x4*)(Kbase + (size_t)(kts * 64 + r1) * C3 + off0);
      u32x4 rv0 = *(const u32x4*)(Vbase + (size_t)r0 * T + kts * 64 + off0);
      u32x4 rv1 = *(const u32x4*)(Vbase + (size_t)r1 * T + kts * 64 + off0);
      __syncthreads();  // prev pass readers (incl. bounce) drained
      *(u32x4*)((char*)lK[0] + r0 * 128 + sb0) = rk0;
      *(u32x4*)((char*)lK[0] + r1 * 128 + sb1) = rk1;
      *(u32x4*)((char*)lV[0] + r0 * 128 + sb0) = rv0;
      *(u32x4*)((char*)lV[0] + r1 * 128 + sb1) = rv1;
      if (nit > 1) {
        rk0 = *(const u32x4*)(Kbase + (size_t)((kts + 1) * 64 + r0) * C3 + off0);
        rk1 = *(const u32x4*)(Kbase + (size_t)((kts + 1) * 64 + r1) * C3 + off0);
        rv0 = *(const u32x4*)(Vbase + (size_t)r0 * T + (kts + 1) * 64 + off0);
        rv1 = *(const u32x4*)(Vbase + (size_t)r1 * T + (kts + 1) * 64 + off0);
      }

      for (int i = 0; i < nit; ++i) {
        const int kt = kts + i;
        const int cur = i & 1;
        __syncthreads();  // buf[cur] visible; buf[cur^1] readers drained
        if (i < nit - 1) {
          *(u32x4*)((char*)lK[cur ^ 1] + r0 * 128 + sb0) = rk0;
          *(u32x4*)((char*)lK[cur ^ 1] + r1 * 128 + sb1) = rk1;
          *(u32x4*)((char*)lV[cur ^ 1] + r0 * 128 + sb0) = rv0;
          *(u32x4*)((char*)lV[cur ^ 1] + r1 * 128 + sb1) = rv1;
          if (i + 1 < nit - 1) {
            const int kn = (kt + 2) * 64;
            rk0 = *(const u32x4*)(Kbase + (size_t)(kn + r0) * C3 + off0);
            rk1 = *(const u32x4*)(Kbase + (size_t)(kn + r1) * C3 + off0);
            rv0 = *(const u32x4*)(Vbase + (size_t)r0 * T + kn + off0);
            rv1 = *(const u32x4*)(Vbase + (size_t)r1 * T + kn + off0);
          }
        }
        const char* Kc = (const char*)lK[cur];
        const char* Vc = (const char*)lV[cur];

        // S^T = K Q^T: lane owns q = qrow; rows kv = kb*32 + (r&3)+8*(r>>2)+4*h5
        f32x16 s0, s1;
#pragma unroll
        for (int r = 0; r < 16; ++r) { s0[r] = 0.f; s1[r] = 0.f; }
        __builtin_amdgcn_s_setprio(1);
#pragma unroll
        for (int ks = 0; ks < 4; ++ks) {
          const int cb = (ks * 32 + h5 * 16);
          bf16x8 kf0 = *(const bf16x8*)(Kc + l31 * 128 + (cb ^ ((l31 & 7) << 4)));
          bf16x8 kf1 = *(const bf16x8*)(Kc + (32 + l31) * 128 + (cb ^ ((l31 & 7) << 4)));
          s0 = __builtin_amdgcn_mfma_f32_32x32x16_bf16(kf0, aq[ks], s0, 0, 0, 0);
          s1 = __builtin_amdgcn_mfma_f32_32x32x16_bf16(kf1, aq[ks], s1, 0, 0, 0);
        }
        __builtin_amdgcn_s_setprio(0);

        // scale + causal mask (only tiles that can cross the diagonal)
        if (kt >= 2 * qt) {
          const int kb0 = kt * 64;
#pragma unroll
          for (int r = 0; r < 16; ++r) {
            const int kvl = (r & 3) + 8 * (r >> 2) + 4 * h5;
            float v0 = s0[r] * qscale;
            float v1 = s1[r] * qscale;
            if (kb0 + kvl > qrow) v0 = -1.0e30f;
            if (kb0 + 32 + kvl > qrow) v1 = -1.0e30f;
            s0[r] = v0; s1[r] = v1;
          }
        } else {
#pragma unroll
          for (int r = 0; r < 16; ++r) { s0[r] *= qscale; s1[r] *= qscale; }
        }

        // row max: 31-op tree + ONE shfl_xor(32)
        float t0 = fmaxf(fmaxf(s0[0], s0[1]), fmaxf(s0[2], s0[3]));
        float t1 = fmaxf(fmaxf(s0[4], s0[5]), fmaxf(s0[6], s0[7]));
        float t2 = fmaxf(fmaxf(s0[8], s0[9]), fmaxf(s0[10], s0[11]));
        float t3 = fmaxf(fmaxf(s0[12], s0[13]), fmaxf(s0[14], s0[15]));
        float t4 = fmaxf(fmaxf(s1[0], s1[1]), fmaxf(s1[2], s1[3]));
        float t5 = fmaxf(fmaxf(s1[4], s1[5]), fmaxf(s1[6], s1[7]));
        float t6 = fmaxf(fmaxf(s1[8], s1[9]), fmaxf(s1[10], s1[11]));
        float t7 = fmaxf(fmaxf(s1[12], s1[13]), fmaxf(s1[14], s1[15]));
        float pmax = fmaxf(fmaxf(fmaxf(t0, t1), fmaxf(t2, t3)),
                           fmaxf(fmaxf(t4, t5), fmaxf(t6, t7)));
        pmax = fmaxf(pmax, __shfl_xor(pmax, 32));

        // defer-max (THR=0, exact); o rescale is lane-local (O^T layout)
        if (!__all(pmax <= m)) {
          const float mnew = fmaxf(m, pmax);
          const float fct = __builtin_amdgcn_exp2f(m - mnew);
          m = mnew;
          l *= fct;
#pragma unroll
          for (int r = 0; r < 16; ++r) { o0[r] *= fct; o1[r] *= fct; }
        }

        // P = exp2(S - m); sum tree + ONE shfl
#pragma unroll
        for (int r = 0; r < 16; ++r) {
          s0[r] = __builtin_amdgcn_exp2f(s0[r] - m);
          s1[r] = __builtin_amdgcn_exp2f(s1[r] - m);
        }
        float u0 = (s0[0] + s0[1]) + (s0[2] + s0[3]);
        float u1 = (s0[4] + s0[5]) + (s0[6] + s0[7]);
        float u2 = (s0[8] + s0[9]) + (s0[10] + s0[11]);
        float u3 = (s0[12] + s0[13]) + (s0[14] + s0[15]);
        float u4 = (s1[0] + s1[1]) + (s1[2] + s1[3]);
        float u5 = (s1[4] + s1[5]) + (s1[6] + s1[7]);
        float u6 = (s1[8] + s1[9]) + (s1[10] + s1[11]);
        float u7 = (s1[12] + s1[13]) + (s1[14] + s1[15]);
        float psum = ((u0 + u1) + (u2 + u3)) + ((u4 + u5) + (u6 + u7));
        psum += __shfl_xor(psum, 32);
        l += psum;

        // pack P -> PV B-operands in-register (cvt_pk + permlane32_swap)
        union { u32x4 u; bf16x8 b; } pb[4];
        {
          unsigned A = cvtpk(s0[0], s0[1]), Bw = cvtpk(s0[2], s0[3]);
          unsigned Cw = cvtpk(s0[4], s0[5]), Dw = cvtpk(s0[6], s0[7]);
          unsigned E = cvtpk(s0[8], s0[9]), F = cvtpk(s0[10], s0[11]);
          unsigned G = cvtpk(s0[12], s0[13]), H = cvtpk(s0[14], s0[15]);
          plswap(A, Cw); plswap(Bw, Dw); plswap(E, G); plswap(F, H);
          pb[0].u = (u32x4){A, Bw, Cw, Dw};
          pb[1].u = (u32x4){E, F, G, H};
        }
        {
          unsigned A = cvtpk(s1[0], s1[1]), Bw = cvtpk(s1[2], s1[3]);
          unsigned Cw = cvtpk(s1[4], s1[5]), Dw = cvtpk(s1[6], s1[7]);
          unsigned E = cvtpk(s1[8], s1[9]), F = cvtpk(s1[10], s1[11]);
          unsigned G = cvtpk(s1[12], s1[13]), H = cvtpk(s1[14], s1[15]);
          plswap(A, Cw); plswap(Bw, Dw); plswap(E, G); plswap(F, H);
          pb[2].u = (u32x4){A, Bw, Cw, Dw};
          pb[3].u = (u32x4){E, F, G, H};
        }

        // O^T += V^T P^T: A = V-frag (rows d), B = P-frag; 8 MFMA
        __builtin_amdgcn_s_setprio(1);
#pragma unroll
        for (int kk = 0; kk < 4; ++kk) {
          const int cb = (kk * 32 + h5 * 16);
          bf16x8 vf0 = *(const bf16x8*)(Vc + l31 * 128 + (cb ^ ((l31 & 7) << 4)));
          bf16x8 vf1 = *(const bf16x8*)(Vc + (32 + l31) * 128 + (cb ^ ((l31 & 7) << 4)));
          o0 = __builtin_amdgcn_mfma_f32_32x32x16_bf16(vf0, pb[kk].b, o0, 0, 0, 0);
          o1 = __builtin_amdgcn_mfma_f32_32x32x16_bf16(vf1, pb[kk].b, o1, 0, 0, 0);
        }
        __builtin_amdgcn_s_setprio(0);
      }
    }

    // epilogue: normalize (lane-local), bounce O^T -> row-major via freed lK,
    // write l-normalized bf16 partial + (m,l)
    __syncthreads();  // all waves done reading lK/lV this pass
    const float li = (l > 0.f) ? __builtin_amdgcn_rcpf(l) : 0.f;
    char* bnc = (char*)lK + w * 4096;  // per-wave 4KB: 32 q-rows x 128B
#pragma unroll
    for (int db = 0; db < 2; ++db) {
#pragma unroll
      for (int rg = 0; rg < 4; ++rg) {
        u16x4 pk4;
        if (db == 0) {
          pk4[0] = f2bf(o0[rg * 4 + 0] * li); pk4[1] = f2bf(o0[rg * 4 + 1] * li);
          pk4[2] = f2bf(o0[rg * 4 + 2] * li); pk4[3] = f2bf(o0[rg * 4 + 3] * li);
        } else {
          pk4[0] = f2bf(o1[rg * 4 + 0] * li); pk4[1] = f2bf(o1[rg * 4 + 1] * li);
          pk4[2] = f2bf(o1[rg * 4 + 2] * li); pk4[3] = f2bf(o1[rg * 4 + 3] * li);
        }
        // d = db*32 + rg*8 + h5*4 + (0..3) -> byte db*64 + rg*16 + h5*8
        *(u16x4*)(bnc + l31 * 128 + db * 64 + rg * 16 + h5 * 8) = pk4;
      }
    }
    // same-wave readback (DS in-order): row l31, half h5 -> coalesced po write
#pragma unroll
    for (int j = 0; j < 4; ++j) {
      u16x8 vv = *(const u16x8*)(bnc + l31 * 128 + h5 * 64 + j * 16);
      *(u16x8*)&pob[((size_t)b * T + q0 + w * 32 + l31) * 1024 + h * 64 + h5 * 32 + j * 8] = vv;
    }
    if (h5 == 0) {
      float* mp = mlf + (size_t)tr * 131072ull + ((size_t)(b * T + qrow) * 16 + h) * 2;
      mp[0] = m;
      mp[1] = l;
    }
  }
}

// ---------------- merge the three kv-thirds ----------------
__global__ __launch_bounds__(256) void merge3(const u16* __restrict__ p0,
                                              const u16* __restrict__ p1,
                                              const u16* __restrict__ p2,
                                              const float* __restrict__ mlf,
                                              u16* __restrict__ y) {
  const int gid = blockIdx.x * 256 + threadIdx.x;   // 524288 threads
  const int row = gid >> 3, d0 = (gid & 7) * 8;     // row in [0, 65536)
  const int bt = row >> 4, hh = row & 15;
  const float m1 = mlf[row * 2], l1 = mlf[row * 2 + 1];
  const float m2 = mlf[131072 + row * 2], l2 = mlf[131072 + row * 2 + 1];
  const float m3 = mlf[262144 + row * 2], l3 = mlf[262144 + row * 2 + 1];
  const float ms = fmaxf(fmaxf(m1, m2), m3);
  const float a1 = l1 * __builtin_amdgcn_exp2f(m1 - ms);
  const float a2 = l2 * __builtin_amdgcn_exp2f(m2 - ms);
  const float a3 = l3 * __builtin_amdgcn_exp2f(m3 - ms);
  const float inv = __builtin_amdgcn_rcpf(a1 + a2 + a3);
  const float w1 = a1 * inv, w2 = a2 * inv, w3 = a3 * inv;
  const size_t off = (size_t)bt * 1024 + hh * 64 + d0;
  u16x8 q1 = *(const u16x8*)&p0[off];
  u16x8 q2 = *(const u16x8*)&p1[off];
  u16x8 q3 = *(const u16x8*)&p2[off];
  u16x8 o;
#pragma unroll
  for (int j = 0; j < 8; ++j)
    o[j] = f2bf(w1 * bf2f(q1[j]) + w2 * bf2f(q2[j]) + w3 * bf2f(q3[j]));
  *(u16x8*)&y[off] = o;
}

extern "C" void kernel_launch(void* const* d_in, const int* in_sizes, int n_in,
                              void* d_out, int out_size, void* d_ws, size_t ws_size,
                              hipStream_t stream) {
  const float* x = (const float*)d_in[0];
  const float* Wqkv = (const float*)d_in[1];
  const float* Wproj = (const float*)d_in[2];
  float* out = (float*)d_out;

  constexpr int B = 2, T = 2048, C = 1024, C3 = 3072, H = 16, D = 64;
  constexpr int M = B * T;  // 4096

  u16* xb = (u16*)d_ws;                       // M*C   (dead after qkv GEMM -> po slice 2)
  u16* wqkvb = xb + (size_t)M * C;            // C3*C
  u16* wprojb = wqkvb + (size_t)C3 * C;       // C*C
  u16* qkvb = wprojb + (size_t)C * C;         // M*C3 (v-part unused)
  u16* vtb = qkvb + (size_t)M * C3;           // B*H*D*T = M*C
  u16* yb = vtb + (size_t)M * C;              // M*C
  u16* po = yb + (size_t)M * C;               // 2 * M*C (slices 0,1)
  float* mlf = (float*)(po + 2ull * M * C);   // 3 * 65536 * 2 floats
  u16* po2 = xb;                              // slice 2 aliases dead xb

  constexpr int n1 = (M * C) / 4, n2 = (C3 * C) / 4, n3 = (C * C) / 4;
  cvt3_f32_bf16<<<dim3((n1 + n2 + n3 + 255) / 256), 256, 0, stream>>>(
      x, Wqkv, Wproj, xb, n1, n2, n3);

  gemm_nt<1, 1><<<dim3((C3 / 128) * (M / 128)), 256, 0, stream>>>(
      xb, wqkvb, qkvb, vtb, M, C3, C, M / 128);
  attn_fwd<<<dim3(768), 256, 0, stream>>>(qkvb, vtb, po, po + (size_t)M * C, po2, mlf);
  merge3<<<dim3(2048), 256, 0, stream>>>(po, po + (size_t)M * C, po2, mlf, yb);
  gemm_nt<0, 0><<<dim3((C / 128) * (M / 128)), 256, 0, stream>>>(
      yb, wprojb, out, nullptr, M, C, C, M / 128);
}

// Round 19
// 264.920 us; speedup vs baseline: 1.0048x; 1.0048x over previous
//
#include <hip/hip_runtime.h>

typedef unsigned short u16;
typedef float f32x4 __attribute__((ext_vector_type(4)));
typedef float f32x16 __attribute__((ext_vector_type(16)));
typedef __bf16 bf16x8 __attribute__((ext_vector_type(8)));
typedef unsigned int u32x4 __attribute__((ext_vector_type(4)));
typedef u16 u16x4 __attribute__((ext_vector_type(4)));
typedef u16 u16x8 __attribute__((ext_vector_type(8)));

static __device__ __forceinline__ u16 f2bf(float f) {
  union { __bf16 h; u16 u; } c;
  c.h = (__bf16)f;
  return c.u;
}
static __device__ __forceinline__ float bf2f(u16 u) {
  union { unsigned u; float f; } c;
  c.u = ((unsigned)u) << 16;
  return c.f;
}
static __device__ __forceinline__ unsigned cvtpk(float a, float b) {
  unsigned r;
  asm volatile("v_cvt_pk_bf16_f32 %0, %1, %2" : "=v"(r) : "v"(a), "v"(b));
  return r;
}
// after: a = [a.lo31 | b.lo31], b = [a.hi31 | b.hi31]
static __device__ __forceinline__ void plswap(unsigned& a, unsigned& b) {
  asm volatile("v_permlane32_swap_b32 %0, %1" : "+v"(a), "+v"(b));
}

static __device__ __forceinline__ void gload_lds16(const void* g, void* l) {
  __builtin_amdgcn_global_load_lds(
      (const __attribute__((address_space(1))) unsigned int*)g,
      (__attribute__((address_space(3))) unsigned int*)l, 16, 0, 0);
}

// ---------------- fused fp32 -> bf16 convert ----------------
__global__ __launch_bounds__(256) void cvt3_f32_bf16(const float* __restrict__ a,
                                                     const float* __restrict__ bb,
                                                     const float* __restrict__ cc,
                                                     u16* __restrict__ out,
                                                     int n1, int n2, int n3) {
  int i = blockIdx.x * 256 + threadIdx.x;
  const float* src;
  int j = i;
  if (i < n1) { src = a; }
  else if (i < n1 + n2) { src = bb; j = i - n1; }
  else { src = cc; j = i - n1 - n2; if (j >= n3) return; }
  f32x4 v = *((const f32x4*)src + j);
  u16x4 o;
  o[0] = f2bf(v[0]); o[1] = f2bf(v[1]); o[2] = f2bf(v[2]); o[3] = f2bf(v[3]);
  *((u16x4*)out + i) = o;
}

// ---------------- 128x128 GEMM (proven m97-structure) ----------------
template<int OUT_BF16, int FUSE_VT>
__global__ __launch_bounds__(256) void gemm_nt(const u16* __restrict__ A,
                                               const u16* __restrict__ B,
                                               void* __restrict__ Cp,
                                               u16* __restrict__ vt,
                                               int M, int N, int K, int gy) {
  __shared__ __align__(16) u16 lA[128 * 64];
  __shared__ __align__(16) u16 lB[128 * 64];
  const int tid = threadIdx.x;
  const int lane = tid & 63;
  const int wave = tid >> 6;
  const int wm = wave >> 1, wn = wave & 1;
  const int l15 = lane & 15, lg = lane >> 4;

  const int bid = blockIdx.x;
  const int xcd = bid & 7, s = bid >> 3;
  const int pnx = (N >> 7) >> 3;
  const int bm = (s % gy) * 128;
  const int bn = (xcd * pnx + s / gy) * 128;

  f32x4 acc[4][4];
#pragma unroll
  for (int i = 0; i < 4; ++i)
#pragma unroll
    for (int j = 0; j < 4; ++j) acc[i][j] = (f32x4){0.f, 0.f, 0.f, 0.f};

  const u16* Ag[4];
  const u16* Bg[4];
#pragma unroll
  for (int it = 0; it < 4; ++it) {
    const int ss = it * 256 + tid;
    const int row = ss >> 3, g = ss & 7;
    const int gsw = g ^ (row & 7);
    Ag[it] = A + (size_t)(bm + row) * K + gsw * 8;
    Bg[it] = B + (size_t)(bn + row) * K + gsw * 8;
  }

  for (int k0 = 0; k0 < K; k0 += 64) {
#pragma unroll
    for (int it = 0; it < 4; ++it) {
      gload_lds16(Ag[it] + k0, (u16*)lA + (size_t)(it * 256 + tid) * 8);
      gload_lds16(Bg[it] + k0, (u16*)lB + (size_t)(it * 256 + tid) * 8);
    }
    __syncthreads();
#pragma unroll
    for (int kk = 0; kk < 2; ++kk) {
      bf16x8 af[4], bfv[4];
#pragma unroll
      for (int mf = 0; mf < 4; ++mf) {
        const int row = wm * 64 + mf * 16 + l15;
        af[mf] = *(const bf16x8*)((const char*)lA + row * 128 +
                                  ((kk * 64 + lg * 16) ^ ((row & 7) << 4)));
      }
#pragma unroll
      for (int nf = 0; nf < 4; ++nf) {
        const int row = wn * 64 + nf * 16 + l15;
        bfv[nf] = *(const bf16x8*)((const char*)lB + row * 128 +
                                   ((kk * 64 + lg * 16) ^ ((row & 7) << 4)));
      }
#pragma unroll
      for (int mf = 0; mf < 4; ++mf)
#pragma unroll
        for (int nf = 0; nf < 4; ++nf)
          acc[mf][nf] = __builtin_amdgcn_mfma_f32_16x16x32_bf16(af[mf], bfv[nf], acc[mf][nf], 0, 0, 0);
    }
    __syncthreads();
  }

  if (FUSE_VT && bn >= 2048) {
#pragma unroll
    for (int mf = 0; mf < 4; ++mf) {
      const int row0 = bm + wm * 64 + mf * 16 + lg * 4;
      const int b = row0 >> 11, t0 = row0 & 2047;
#pragma unroll
      for (int nf = 0; nf < 4; ++nf) {
        const int colv = bn - 2048 + wn * 64 + nf * 16 + l15;
        const int h = colv >> 6, d = colv & 63;
        u16x4 pk;
        pk[0] = f2bf(acc[mf][nf][0]); pk[1] = f2bf(acc[mf][nf][1]);
        pk[2] = f2bf(acc[mf][nf][2]); pk[3] = f2bf(acc[mf][nf][3]);
        *(u16x4*)&vt[((size_t)((b * 16 + h) * 64 + d)) * 2048 + t0] = pk;
      }
    }
  } else {
#pragma unroll
    for (int mf = 0; mf < 4; ++mf) {
#pragma unroll
      for (int r = 0; r < 4; ++r) {
        const int row = bm + wm * 64 + mf * 16 + lg * 4 + r;
#pragma unroll
        for (int nf = 0; nf < 4; ++nf) {
          const int col = bn + wn * 64 + nf * 16 + l15;
          const float v = acc[mf][nf][r];
          if (OUT_BF16) ((u16*)Cp)[(size_t)row * N + col] = f2bf(v);
          else          ((float*)Cp)[(size_t)row * N + col] = v;
        }
      }
    }
  }
}

// ---------------- flash attention fwd (causal), 32x32 MFMA, 4 waves ----------------
// Same verified math as R18 (passed absmax 3.9e-3); ALL aggregates (arrays/
// unions) replaced with named registers + __builtin_bit_cast to kill the
// scratch spill (R18: WRITE_SIZE 448MB, VGPR 84 -> spilled).
__global__ __launch_bounds__(256, 3) void attn_fwd(const u16* __restrict__ qkv,
                                                   const u16* __restrict__ vt,
                                                   u16* __restrict__ po0,
                                                   u16* __restrict__ po1,
                                                   u16* __restrict__ po2,
                                                   float* __restrict__ mlf) {
  constexpr int T = 2048, C3 = 3072;
  __shared__ __align__(16) u16 lK[2][64 * 64];
  __shared__ __align__(16) u16 lV[2][64 * 64];
  const int tid = threadIdx.x, lane = tid & 63, w = tid >> 6;  // 4 waves
  const int l31 = lane & 31, h5 = lane >> 5;

  const int bid = blockIdx.x;                 // 768 blocks
  const int xcd = bid & 7, slot = bid >> 3;   // 96 per xcd
  const int bh = xcd * 4 + slot / 24;
  const int rem = slot % 24;
  const int pi = rem / 3, tr = rem % 3;
  const int b = bh >> 4, h = bh & 15;

  const int r0 = tid >> 3, off0 = (tid & 7) * 8;
  const int r1 = r0 + 32;
  const int sb0 = (off0 * 2) ^ ((r0 & 7) << 4);
  const int sb1 = (off0 * 2) ^ ((r1 & 7) << 4);
  const u16* Kbase = qkv + (size_t)b * T * C3 + 1024 + h * 64;
  const u16* Vbase = vt + (size_t)bh * 64 * T;
  u16* pob = (tr == 0) ? po0 : ((tr == 1) ? po1 : po2);

  const float qscale = 0.125f * 1.44269504088896f;  // scale * log2(e)

#pragma unroll 1
  for (int qi = 0; qi < 2; ++qi) {
    const int qt = (qi == 0) ? pi : (15 - pi);
    const int q0 = qt * 128;
    const int n = 2 * qt + 2;
    const int kts = tr * n / 3, kte = (tr + 1) * n / 3;
    const int nit = kte - kts;
    const int qrow = q0 + w * 32 + l31;

    const size_t qoff = ((size_t)b * T + qrow) * C3 + h * 64;
    const bf16x8 aq0 = *(const bf16x8*)&qkv[qoff + 0 * 16 + h5 * 8];
    const bf16x8 aq1 = *(const bf16x8*)&qkv[qoff + 1 * 16 + h5 * 8];
    const bf16x8 aq2 = *(const bf16x8*)&qkv[qoff + 2 * 16 + h5 * 8];
    const bf16x8 aq3 = *(const bf16x8*)&qkv[qoff + 3 * 16 + h5 * 8];

    float m = -1.0e30f, l = 0.f;
    f32x16 o0, o1;
#pragma unroll
    for (int r = 0; r < 16; ++r) { o0[r] = 0.f; o1[r] = 0.f; }

    if (nit > 0) {
      u32x4 rk0 = *(const u32x4*)(Kbase + (size_t)(kts * 64 + r0) * C3 + off0);
      u32x4 rk1 = *(const u32x4*)(Kbase + (size_t)(kts * 64 + r1) * C3 + off0);
      u32x4 rv0 = *(const u32x4*)(Vbase + (size_t)r0 * T + kts * 64 + off0);
      u32x4 rv1 = *(const u32x4*)(Vbase + (size_t)r1 * T + kts * 64 + off0);
      __syncthreads();  // prev pass readers (incl. bounce) drained
      *(u32x4*)((char*)lK[0] + r0 * 128 + sb0) = rk0;
      *(u32x4*)((char*)lK[0] + r1 * 128 + sb1) = rk1;
      *(u32x4*)((char*)lV[0] + r0 * 128 + sb0) = rv0;
      *(u32x4*)((char*)lV[0] + r1 * 128 + sb1) = rv1;
      if (nit > 1) {
        rk0 = *(const u32x4*)(Kbase + (size_t)((kts + 1) * 64 + r0) * C3 + off0);
        rk1 = *(const u32x4*)(Kbase + (size_t)((kts + 1) * 64 + r1) * C3 + off0);
        rv0 = *(const u32x4*)(Vbase + (size_t)r0 * T + (kts + 1) * 64 + off0);
        rv1 = *(const u32x4*)(Vbase + (size_t)r1 * T + (kts + 1) * 64 + off0);
      }

      for (int i = 0; i < nit; ++i) {
        const int kt = kts + i;
        const int cur = i & 1;
        __syncthreads();  // buf[cur] visible; buf[cur^1] readers drained
        if (i < nit - 1) {
          *(u32x4*)((char*)lK[cur ^ 1] + r0 * 128 + sb0) = rk0;
          *(u32x4*)((char*)lK[cur ^ 1] + r1 * 128 + sb1) = rk1;
          *(u32x4*)((char*)lV[cur ^ 1] + r0 * 128 + sb0) = rv0;
          *(u32x4*)((char*)lV[cur ^ 1] + r1 * 128 + sb1) = rv1;
          if (i + 1 < nit - 1) {
            const int kn = (kt + 2) * 64;
            rk0 = *(const u32x4*)(Kbase + (size_t)(kn + r0) * C3 + off0);
            rk1 = *(const u32x4*)(Kbase + (size_t)(kn + r1) * C3 + off0);
            rv0 = *(const u32x4*)(Vbase + (size_t)r0 * T + kn + off0);
            rv1 = *(const u32x4*)(Vbase + (size_t)r1 * T + kn + off0);
          }
        }
        const char* Kc = (const char*)lK[cur];
        const char* Vc = (const char*)lV[cur];

        // S^T = K Q^T: lane owns q = qrow; rows kv = kb*32 + (r&3)+8*(r>>2)+4*h5
        f32x16 s0, s1;
#pragma unroll
        for (int r = 0; r < 16; ++r) { s0[r] = 0.f; s1[r] = 0.f; }
        __builtin_amdgcn_s_setprio(1);
#define QK_STEP(KS, AQ)                                                         \
        {                                                                       \
          const int cb = (KS * 32 + h5 * 16);                                   \
          bf16x8 kf0 = *(const bf16x8*)(Kc + l31 * 128 + (cb ^ ((l31 & 7) << 4))); \
          bf16x8 kf1 = *(const bf16x8*)(Kc + (32 + l31) * 128 + (cb ^ ((l31 & 7) << 4))); \
          s0 = __builtin_amdgcn_mfma_f32_32x32x16_bf16(kf0, AQ, s0, 0, 0, 0);   \
          s1 = __builtin_amdgcn_mfma_f32_32x32x16_bf16(kf1, AQ, s1, 0, 0, 0);   \
        }
        QK_STEP(0, aq0)
        QK_STEP(1, aq1)
        QK_STEP(2, aq2)
        QK_STEP(3, aq3)
#undef QK_STEP
        __builtin_amdgcn_s_setprio(0);

        // scale + causal mask (only tiles that can cross the diagonal)
        if (kt >= 2 * qt) {
          const int kb0 = kt * 64;
#pragma unroll
          for (int r = 0; r < 16; ++r) {
            const int kvl = (r & 3) + 8 * (r >> 2) + 4 * h5;
            float v0 = s0[r] * qscale;
            float v1 = s1[r] * qscale;
            if (kb0 + kvl > qrow) v0 = -1.0e30f;
            if (kb0 + 32 + kvl > qrow) v1 = -1.0e30f;
            s0[r] = v0; s1[r] = v1;
          }
        } else {
#pragma unroll
          for (int r = 0; r < 16; ++r) { s0[r] *= qscale; s1[r] *= qscale; }
        }

        // row max: 31-op tree + ONE shfl_xor(32)
        float t0 = fmaxf(fmaxf(s0[0], s0[1]), fmaxf(s0[2], s0[3]));
        float t1 = fmaxf(fmaxf(s0[4], s0[5]), fmaxf(s0[6], s0[7]));
        float t2 = fmaxf(fmaxf(s0[8], s0[9]), fmaxf(s0[10], s0[11]));
        float t3 = fmaxf(fmaxf(s0[12], s0[13]), fmaxf(s0[14], s0[15]));
        float t4 = fmaxf(fmaxf(s1[0], s1[1]), fmaxf(s1[2], s1[3]));
        float t5 = fmaxf(fmaxf(s1[4], s1[5]), fmaxf(s1[6], s1[7]));
        float t6 = fmaxf(fmaxf(s1[8], s1[9]), fmaxf(s1[10], s1[11]));
        float t7 = fmaxf(fmaxf(s1[12], s1[13]), fmaxf(s1[14], s1[15]));
        float pmax = fmaxf(fmaxf(fmaxf(t0, t1), fmaxf(t2, t3)),
                           fmaxf(fmaxf(t4, t5), fmaxf(t6, t7)));
        pmax = fmaxf(pmax, __shfl_xor(pmax, 32));

        // defer-max (THR=0, exact); o rescale is lane-local (O^T layout)
        if (!__all(pmax <= m)) {
          const float mnew = fmaxf(m, pmax);
          const float fct = __builtin_amdgcn_exp2f(m - mnew);
          m = mnew;
          l *= fct;
#pragma unroll
          for (int r = 0; r < 16; ++r) { o0[r] *= fct; o1[r] *= fct; }
        }

        // P = exp2(S - m); sum tree + ONE shfl
#pragma unroll
        for (int r = 0; r < 16; ++r) {
          s0[r] = __builtin_amdgcn_exp2f(s0[r] - m);
          s1[r] = __builtin_amdgcn_exp2f(s1[r] - m);
        }
        float u0 = (s0[0] + s0[1]) + (s0[2] + s0[3]);
        float u1 = (s0[4] + s0[5]) + (s0[6] + s0[7]);
        float u2 = (s0[8] + s0[9]) + (s0[10] + s0[11]);
        float u3 = (s0[12] + s0[13]) + (s0[14] + s0[15]);
        float u4 = (s1[0] + s1[1]) + (s1[2] + s1[3]);
        float u5 = (s1[4] + s1[5]) + (s1[6] + s1[7]);
        float u6 = (s1[8] + s1[9]) + (s1[10] + s1[11]);
        float u7 = (s1[12] + s1[13]) + (s1[14] + s1[15]);
        float psum = ((u0 + u1) + (u2 + u3)) + ((u4 + u5) + (u6 + u7));
        psum += __shfl_xor(psum, 32);
        l += psum;

        // pack P -> PV B-operands in NAMED registers (no arrays/unions)
        unsigned pA0 = cvtpk(s0[0], s0[1]), pA1 = cvtpk(s0[2], s0[3]);
        unsigned pA2 = cvtpk(s0[4], s0[5]), pA3 = cvtpk(s0[6], s0[7]);
        unsigned pB0 = cvtpk(s0[8], s0[9]), pB1 = cvtpk(s0[10], s0[11]);
        unsigned pB2 = cvtpk(s0[12], s0[13]), pB3 = cvtpk(s0[14], s0[15]);
        plswap(pA0, pA2); plswap(pA1, pA3); plswap(pB0, pB2); plswap(pB1, pB3);
        unsigned pC0 = cvtpk(s1[0], s1[1]), pC1 = cvtpk(s1[2], s1[3]);
        unsigned pC2 = cvtpk(s1[4], s1[5]), pC3 = cvtpk(s1[6], s1[7]);
        unsigned pD0 = cvtpk(s1[8], s1[9]), pD1 = cvtpk(s1[10], s1[11]);
        unsigned pD2 = cvtpk(s1[12], s1[13]), pD3 = cvtpk(s1[14], s1[15]);
        plswap(pC0, pC2); plswap(pC1, pC3); plswap(pD0, pD2); plswap(pD1, pD3);
        const bf16x8 pbA = __builtin_bit_cast(bf16x8, (u32x4){pA0, pA1, pA2, pA3});
        const bf16x8 pbB = __builtin_bit_cast(bf16x8, (u32x4){pB0, pB1, pB2, pB3});
        const bf16x8 pbC = __builtin_bit_cast(bf16x8, (u32x4){pC0, pC1, pC2, pC3});
        const bf16x8 pbD = __builtin_bit_cast(bf16x8, (u32x4){pD0, pD1, pD2, pD3});

        // O^T += V^T P^T: A = V-frag (rows d), B = P-frag; 8 MFMA
        __builtin_amdgcn_s_setprio(1);
#define PV_STEP(KK, PB)                                                         \
        {                                                                       \
          const int cb = (KK * 32 + h5 * 16);                                   \
          bf16x8 vf0 = *(const bf16x8*)(Vc + l31 * 128 + (cb ^ ((l31 & 7) << 4))); \
          bf16x8 vf1 = *(const bf16x8*)(Vc + (32 + l31) * 128 + (cb ^ ((l31 & 7) << 4))); \
          o0 = __builtin_amdgcn_mfma_f32_32x32x16_bf16(vf0, PB, o0, 0, 0, 0);   \
          o1 = __builtin_amdgcn_mfma_f32_32x32x16_bf16(vf1, PB, o1, 0, 0, 0);   \
        }
        PV_STEP(0, pbA)
        PV_STEP(1, pbB)
        PV_STEP(2, pbC)
        PV_STEP(3, pbD)
#undef PV_STEP
        __builtin_amdgcn_s_setprio(0);
      }
    }

    // epilogue: normalize (lane-local), bounce O^T -> row-major via freed lK,
    // write l-normalized bf16 partial + (m,l)
    __syncthreads();  // all waves done reading lK/lV this pass
    const float li = (l > 0.f) ? __builtin_amdgcn_rcpf(l) : 0.f;
    char* bnc = (char*)lK + w * 4096;  // per-wave 4KB: 32 q-rows x 128B
#pragma unroll
    for (int rg = 0; rg < 4; ++rg) {
      u16x4 pk4;
      pk4[0] = f2bf(o0[rg * 4 + 0] * li); pk4[1] = f2bf(o0[rg * 4 + 1] * li);
      pk4[2] = f2bf(o0[rg * 4 + 2] * li); pk4[3] = f2bf(o0[rg * 4 + 3] * li);
      *(u16x4*)(bnc + l31 * 128 + 0 * 64 + rg * 16 + h5 * 8) = pk4;
    }
#pragma unroll
    for (int rg = 0; rg < 4; ++rg) {
      u16x4 pk4;
      pk4[0] = f2bf(o1[rg * 4 + 0] * li); pk4[1] = f2bf(o1[rg * 4 + 1] * li);
      pk4[2] = f2bf(o1[rg * 4 + 2] * li); pk4[3] = f2bf(o1[rg * 4 + 3] * li);
      *(u16x4*)(bnc + l31 * 128 + 1 * 64 + rg * 16 + h5 * 8) = pk4;
    }
    // same-wave readback (DS in-order): row l31, half h5 -> coalesced po write
#pragma unroll
    for (int j = 0; j < 4; ++j) {
      u16x8 vv = *(const u16x8*)(bnc + l31 * 128 + h5 * 64 + j * 16);
      *(u16x8*)&pob[((size_t)b * T + q0 + w * 32 + l31) * 1024 + h * 64 + h5 * 32 + j * 8] = vv;
    }
    if (h5 == 0) {
      float* mp = mlf + (size_t)tr * 131072ull + ((size_t)(b * T + qrow) * 16 + h) * 2;
      mp[0] = m;
      mp[1] = l;
    }
  }
}

// ---------------- merge the three kv-thirds ----------------
__global__ __launch_bounds__(256) void merge3(const u16* __restrict__ p0,
                                              const u16* __restrict__ p1,
                                              const u16* __restrict__ p2,
                                              const float* __restrict__ mlf,
                                              u16* __restrict__ y) {
  const int gid = blockIdx.x * 256 + threadIdx.x;   // 524288 threads
  const int row = gid >> 3, d0 = (gid & 7) * 8;     // row in [0, 65536)
  const int bt = row >> 4, hh = row & 15;
  const float m1 = mlf[row * 2], l1 = mlf[row * 2 + 1];
  const float m2 = mlf[131072 + row * 2], l2 = mlf[131072 + row * 2 + 1];
  const float m3 = mlf[262144 + row * 2], l3 = mlf[262144 + row * 2 + 1];
  const float ms = fmaxf(fmaxf(m1, m2), m3);
  const float a1 = l1 * __builtin_amdgcn_exp2f(m1 - ms);
  const float a2 = l2 * __builtin_amdgcn_exp2f(m2 - ms);
  const float a3 = l3 * __builtin_amdgcn_exp2f(m3 - ms);
  const float inv = __builtin_amdgcn_rcpf(a1 + a2 + a3);
  const float w1 = a1 * inv, w2 = a2 * inv, w3 = a3 * inv;
  const size_t off = (size_t)bt * 1024 + hh * 64 + d0;
  u16x8 q1 = *(const u16x8*)&p0[off];
  u16x8 q2 = *(const u16x8*)&p1[off];
  u16x8 q3 = *(const u16x8*)&p2[off];
  u16x8 o;
#pragma unroll
  for (int j = 0; j < 8; ++j)
    o[j] = f2bf(w1 * bf2f(q1[j]) + w2 * bf2f(q2[j]) + w3 * bf2f(q3[j]));
  *(u16x8*)&y[off] = o;
}

extern "C" void kernel_launch(void* const* d_in, const int* in_sizes, int n_in,
                              void* d_out, int out_size, void* d_ws, size_t ws_size,
                              hipStream_t stream) {
  const float* x = (const float*)d_in[0];
  const float* Wqkv = (const float*)d_in[1];
  const float* Wproj = (const float*)d_in[2];
  float* out = (float*)d_out;

  constexpr int B = 2, T = 2048, C = 1024, C3 = 3072, H = 16, D = 64;
  constexpr int M = B * T;  // 4096

  u16* xb = (u16*)d_ws;                       // M*C   (dead after qkv GEMM -> po slice 2)
  u16* wqkvb = xb + (size_t)M * C;            // C3*C
  u16* wprojb = wqkvb + (size_t)C3 * C;       // C*C
  u16* qkvb = wprojb + (size_t)C * C;         // M*C3 (v-part unused)
  u16* vtb = qkvb + (size_t)M * C3;           // B*H*D*T = M*C
  u16* yb = vtb + (size_t)M * C;              // M*C
  u16* po = yb + (size_t)M * C;               // 2 * M*C (slices 0,1)
  float* mlf = (float*)(po + 2ull * M * C);   // 3 * 65536 * 2 floats
  u16* po2 = xb;                              // slice 2 aliases dead xb

  constexpr int n1 = (M * C) / 4, n2 = (C3 * C) / 4, n3 = (C * C) / 4;
  cvt3_f32_bf16<<<dim3((n1 + n2 + n3 + 255) / 256), 256, 0, stream>>>(
      x, Wqkv, Wproj, xb, n1, n2, n3);

  gemm_nt<1, 1><<<dim3((C3 / 128) * (M / 128)), 256, 0, stream>>>(
      xb, wqkvb, qkvb, vtb, M, C3, C, M / 128);
  attn_fwd<<<dim3(768), 256, 0, stream>>>(qkvb, vtb, po, po + (size_t)M * C, po2, mlf);
  merge3<<<dim3(2048), 256, 0, stream>>>(po, po + (size_t)M * C, po2, mlf, yb);
  gemm_nt<0, 0><<<dim3((C / 128) * (M / 128)), 256, 0, stream>>>(
      yb, wprojb, out, nullptr, M, C, C, M / 128);
}

// Round 20
// 123.187 us; speedup vs baseline: 2.1610x; 2.1505x over previous
//
#include <hip/hip_runtime.h>

typedef unsigned short u16;
typedef float f32x4 __attribute__((ext_vector_type(4)));
typedef float f32x16 __attribute__((ext_vector_type(16)));
typedef __bf16 bf16x8 __attribute__((ext_vector_type(8)));
typedef unsigned int u32x4 __attribute__((ext_vector_type(4)));
typedef u16 u16x4 __attribute__((ext_vector_type(4)));
typedef u16 u16x8 __attribute__((ext_vector_type(8)));

static __device__ __forceinline__ u16 f2bf(float f) {
  union { __bf16 h; u16 u; } c;
  c.h = (__bf16)f;
  return c.u;
}
static __device__ __forceinline__ float bf2f(u16 u) {
  union { unsigned u; float f; } c;
  c.u = ((unsigned)u) << 16;
  return c.f;
}
static __device__ __forceinline__ unsigned cvtpk(float a, float b) {
  unsigned r;
  asm volatile("v_cvt_pk_bf16_f32 %0, %1, %2" : "=v"(r) : "v"(a), "v"(b));
  return r;
}
// after: a = [a.lo31 | b.lo31], b = [a.hi31 | b.hi31]
static __device__ __forceinline__ void plswap(unsigned& a, unsigned& b) {
  asm volatile("v_permlane32_swap_b32 %0, %1" : "+v"(a), "+v"(b));
}

static __device__ __forceinline__ void gload_lds16(const void* g, void* l) {
  __builtin_amdgcn_global_load_lds(
      (const __attribute__((address_space(1))) unsigned int*)g,
      (__attribute__((address_space(3))) unsigned int*)l, 16, 0, 0);
}

// ---------------- fused fp32 -> bf16 convert ----------------
__global__ __launch_bounds__(256) void cvt3_f32_bf16(const float* __restrict__ a,
                                                     const float* __restrict__ bb,
                                                     const float* __restrict__ cc,
                                                     u16* __restrict__ out,
                                                     int n1, int n2, int n3) {
  int i = blockIdx.x * 256 + threadIdx.x;
  const float* src;
  int j = i;
  if (i < n1) { src = a; }
  else if (i < n1 + n2) { src = bb; j = i - n1; }
  else { src = cc; j = i - n1 - n2; if (j >= n3) return; }
  f32x4 v = *((const f32x4*)src + j);
  u16x4 o;
  o[0] = f2bf(v[0]); o[1] = f2bf(v[1]); o[2] = f2bf(v[2]); o[3] = f2bf(v[3]);
  *((u16x4*)out + i) = o;
}

// ---------------- 128x128 GEMM (proven m97-structure) ----------------
template<int OUT_BF16, int FUSE_VT>
__global__ __launch_bounds__(256) void gemm_nt(const u16* __restrict__ A,
                                               const u16* __restrict__ B,
                                               void* __restrict__ Cp,
                                               u16* __restrict__ vt,
                                               int M, int N, int K, int gy) {
  __shared__ __align__(16) u16 lA[128 * 64];
  __shared__ __align__(16) u16 lB[128 * 64];
  const int tid = threadIdx.x;
  const int lane = tid & 63;
  const int wave = tid >> 6;
  const int wm = wave >> 1, wn = wave & 1;
  const int l15 = lane & 15, lg = lane >> 4;

  const int bid = blockIdx.x;
  const int xcd = bid & 7, s = bid >> 3;
  const int pnx = (N >> 7) >> 3;
  const int bm = (s % gy) * 128;
  const int bn = (xcd * pnx + s / gy) * 128;

  f32x4 acc[4][4];
#pragma unroll
  for (int i = 0; i < 4; ++i)
#pragma unroll
    for (int j = 0; j < 4; ++j) acc[i][j] = (f32x4){0.f, 0.f, 0.f, 0.f};

  const u16* Ag[4];
  const u16* Bg[4];
#pragma unroll
  for (int it = 0; it < 4; ++it) {
    const int ss = it * 256 + tid;
    const int row = ss >> 3, g = ss & 7;
    const int gsw = g ^ (row & 7);
    Ag[it] = A + (size_t)(bm + row) * K + gsw * 8;
    Bg[it] = B + (size_t)(bn + row) * K + gsw * 8;
  }

  for (int k0 = 0; k0 < K; k0 += 64) {
#pragma unroll
    for (int it = 0; it < 4; ++it) {
      gload_lds16(Ag[it] + k0, (u16*)lA + (size_t)(it * 256 + tid) * 8);
      gload_lds16(Bg[it] + k0, (u16*)lB + (size_t)(it * 256 + tid) * 8);
    }
    __syncthreads();
#pragma unroll
    for (int kk = 0; kk < 2; ++kk) {
      bf16x8 af[4], bfv[4];
#pragma unroll
      for (int mf = 0; mf < 4; ++mf) {
        const int row = wm * 64 + mf * 16 + l15;
        af[mf] = *(const bf16x8*)((const char*)lA + row * 128 +
                                  ((kk * 64 + lg * 16) ^ ((row & 7) << 4)));
      }
#pragma unroll
      for (int nf = 0; nf < 4; ++nf) {
        const int row = wn * 64 + nf * 16 + l15;
        bfv[nf] = *(const bf16x8*)((const char*)lB + row * 128 +
                                   ((kk * 64 + lg * 16) ^ ((row & 7) << 4)));
      }
#pragma unroll
      for (int mf = 0; mf < 4; ++mf)
#pragma unroll
        for (int nf = 0; nf < 4; ++nf)
          acc[mf][nf] = __builtin_amdgcn_mfma_f32_16x16x32_bf16(af[mf], bfv[nf], acc[mf][nf], 0, 0, 0);
    }
    __syncthreads();
  }

  if (FUSE_VT && bn >= 2048) {
#pragma unroll
    for (int mf = 0; mf < 4; ++mf) {
      const int row0 = bm + wm * 64 + mf * 16 + lg * 4;
      const int b = row0 >> 11, t0 = row0 & 2047;
#pragma unroll
      for (int nf = 0; nf < 4; ++nf) {
        const int colv = bn - 2048 + wn * 64 + nf * 16 + l15;
        const int h = colv >> 6, d = colv & 63;
        u16x4 pk;
        pk[0] = f2bf(acc[mf][nf][0]); pk[1] = f2bf(acc[mf][nf][1]);
        pk[2] = f2bf(acc[mf][nf][2]); pk[3] = f2bf(acc[mf][nf][3]);
        *(u16x4*)&vt[((size_t)((b * 16 + h) * 64 + d)) * 2048 + t0] = pk;
      }
    }
  } else {
#pragma unroll
    for (int mf = 0; mf < 4; ++mf) {
#pragma unroll
      for (int r = 0; r < 4; ++r) {
        const int row = bm + wm * 64 + mf * 16 + lg * 4 + r;
#pragma unroll
        for (int nf = 0; nf < 4; ++nf) {
          const int col = bn + wn * 64 + nf * 16 + l15;
          const float v = acc[mf][nf][r];
          if (OUT_BF16) ((u16*)Cp)[(size_t)row * N + col] = f2bf(v);
          else          ((float*)Cp)[(size_t)row * N + col] = v;
        }
      }
    }
  }
}

// ---------------- flash attention fwd (causal), 32x32 MFMA, 4 waves ----------------
// Math verified (absmax 3.9e-3 in R18/R19). R18/19 spilled because
// __launch_bounds__(256,3) clamped VGPR to 84 (~512/6) < ~150 live state.
// Fix: (256,2) -> compiler allocates what it needs; occupancy settles at
// ~3 waves/SIMD naturally.
__global__ __launch_bounds__(256, 2) void attn_fwd(const u16* __restrict__ qkv,
                                                   const u16* __restrict__ vt,
                                                   u16* __restrict__ po0,
                                                   u16* __restrict__ po1,
                                                   u16* __restrict__ po2,
                                                   float* __restrict__ mlf) {
  constexpr int T = 2048, C3 = 3072;
  __shared__ __align__(16) u16 lK[2][64 * 64];
  __shared__ __align__(16) u16 lV[2][64 * 64];
  const int tid = threadIdx.x, lane = tid & 63, w = tid >> 6;  // 4 waves
  const int l31 = lane & 31, h5 = lane >> 5;

  const int bid = blockIdx.x;                 // 768 blocks
  const int xcd = bid & 7, slot = bid >> 3;   // 96 per xcd
  const int bh = xcd * 4 + slot / 24;
  const int rem = slot % 24;
  const int pi = rem / 3, tr = rem % 3;
  const int b = bh >> 4, h = bh & 15;

  const int r0 = tid >> 3, off0 = (tid & 7) * 8;
  const int r1 = r0 + 32;
  const int sb0 = (off0 * 2) ^ ((r0 & 7) << 4);
  const int sb1 = (off0 * 2) ^ ((r1 & 7) << 4);
  const u16* Kbase = qkv + (size_t)b * T * C3 + 1024 + h * 64;
  const u16* Vbase = vt + (size_t)bh * 64 * T;
  u16* pob = (tr == 0) ? po0 : ((tr == 1) ? po1 : po2);

  const float qscale = 0.125f * 1.44269504088896f;  // scale * log2(e)

#pragma unroll 1
  for (int qi = 0; qi < 2; ++qi) {
    const int qt = (qi == 0) ? pi : (15 - pi);
    const int q0 = qt * 128;
    const int n = 2 * qt + 2;
    const int kts = tr * n / 3, kte = (tr + 1) * n / 3;
    const int nit = kte - kts;
    const int qrow = q0 + w * 32 + l31;

    const size_t qoff = ((size_t)b * T + qrow) * C3 + h * 64;
    const bf16x8 aq0 = *(const bf16x8*)&qkv[qoff + 0 * 16 + h5 * 8];
    const bf16x8 aq1 = *(const bf16x8*)&qkv[qoff + 1 * 16 + h5 * 8];
    const bf16x8 aq2 = *(const bf16x8*)&qkv[qoff + 2 * 16 + h5 * 8];
    const bf16x8 aq3 = *(const bf16x8*)&qkv[qoff + 3 * 16 + h5 * 8];

    float m = -1.0e30f, l = 0.f;
    f32x16 o0, o1;
#pragma unroll
    for (int r = 0; r < 16; ++r) { o0[r] = 0.f; o1[r] = 0.f; }

    if (nit > 0) {
      u32x4 rk0 = *(const u32x4*)(Kbase + (size_t)(kts * 64 + r0) * C3 + off0);
      u32x4 rk1 = *(const u32x4*)(Kbase + (size_t)(kts * 64 + r1) * C3 + off0);
      u32x4 rv0 = *(const u32x4*)(Vbase + (size_t)r0 * T + kts * 64 + off0);
      u32x4 rv1 = *(const u32x4*)(Vbase + (size_t)r1 * T + kts * 64 + off0);
      __syncthreads();  // prev pass readers (incl. bounce) drained
      *(u32x4*)((char*)lK[0] + r0 * 128 + sb0) = rk0;
      *(u32x4*)((char*)lK[0] + r1 * 128 + sb1) = rk1;
      *(u32x4*)((char*)lV[0] + r0 * 128 + sb0) = rv0;
      *(u32x4*)((char*)lV[0] + r1 * 128 + sb1) = rv1;
      if (nit > 1) {
        rk0 = *(const u32x4*)(Kbase + (size_t)((kts + 1) * 64 + r0) * C3 + off0);
        rk1 = *(const u32x4*)(Kbase + (size_t)((kts + 1) * 64 + r1) * C3 + off0);
        rv0 = *(const u32x4*)(Vbase + (size_t)r0 * T + (kts + 1) * 64 + off0);
        rv1 = *(const u32x4*)(Vbase + (size_t)r1 * T + (kts + 1) * 64 + off0);
      }

      for (int i = 0; i < nit; ++i) {
        const int kt = kts + i;
        const int cur = i & 1;
        __syncthreads();  // buf[cur] visible; buf[cur^1] readers drained
        if (i < nit - 1) {
          *(u32x4*)((char*)lK[cur ^ 1] + r0 * 128 + sb0) = rk0;
          *(u32x4*)((char*)lK[cur ^ 1] + r1 * 128 + sb1) = rk1;
          *(u32x4*)((char*)lV[cur ^ 1] + r0 * 128 + sb0) = rv0;
          *(u32x4*)((char*)lV[cur ^ 1] + r1 * 128 + sb1) = rv1;
          if (i + 1 < nit - 1) {
            const int kn = (kt + 2) * 64;
            rk0 = *(const u32x4*)(Kbase + (size_t)(kn + r0) * C3 + off0);
            rk1 = *(const u32x4*)(Kbase + (size_t)(kn + r1) * C3 + off0);
            rv0 = *(const u32x4*)(Vbase + (size_t)r0 * T + kn + off0);
            rv1 = *(const u32x4*)(Vbase + (size_t)r1 * T + kn + off0);
          }
        }
        const char* Kc = (const char*)lK[cur];
        const char* Vc = (const char*)lV[cur];

        // S^T = K Q^T: lane owns q = qrow; rows kv = kb*32 + (r&3)+8*(r>>2)+4*h5
        f32x16 s0, s1;
#pragma unroll
        for (int r = 0; r < 16; ++r) { s0[r] = 0.f; s1[r] = 0.f; }
        __builtin_amdgcn_s_setprio(1);
#define QK_STEP(KS, AQ)                                                         \
        {                                                                       \
          const int cb = (KS * 32 + h5 * 16);                                   \
          bf16x8 kf0 = *(const bf16x8*)(Kc + l31 * 128 + (cb ^ ((l31 & 7) << 4))); \
          bf16x8 kf1 = *(const bf16x8*)(Kc + (32 + l31) * 128 + (cb ^ ((l31 & 7) << 4))); \
          s0 = __builtin_amdgcn_mfma_f32_32x32x16_bf16(kf0, AQ, s0, 0, 0, 0);   \
          s1 = __builtin_amdgcn_mfma_f32_32x32x16_bf16(kf1, AQ, s1, 0, 0, 0);   \
        }
        QK_STEP(0, aq0)
        QK_STEP(1, aq1)
        QK_STEP(2, aq2)
        QK_STEP(3, aq3)
#undef QK_STEP
        __builtin_amdgcn_s_setprio(0);

        // scale + causal mask (only tiles that can cross the diagonal)
        if (kt >= 2 * qt) {
          const int kb0 = kt * 64;
#pragma unroll
          for (int r = 0; r < 16; ++r) {
            const int kvl = (r & 3) + 8 * (r >> 2) + 4 * h5;
            float v0 = s0[r] * qscale;
            float v1 = s1[r] * qscale;
            if (kb0 + kvl > qrow) v0 = -1.0e30f;
            if (kb0 + 32 + kvl > qrow) v1 = -1.0e30f;
            s0[r] = v0; s1[r] = v1;
          }
        } else {
#pragma unroll
          for (int r = 0; r < 16; ++r) { s0[r] *= qscale; s1[r] *= qscale; }
        }

        // row max: 31-op tree + ONE shfl_xor(32)
        float t0 = fmaxf(fmaxf(s0[0], s0[1]), fmaxf(s0[2], s0[3]));
        float t1 = fmaxf(fmaxf(s0[4], s0[5]), fmaxf(s0[6], s0[7]));
        float t2 = fmaxf(fmaxf(s0[8], s0[9]), fmaxf(s0[10], s0[11]));
        float t3 = fmaxf(fmaxf(s0[12], s0[13]), fmaxf(s0[14], s0[15]));
        float t4 = fmaxf(fmaxf(s1[0], s1[1]), fmaxf(s1[2], s1[3]));
        float t5 = fmaxf(fmaxf(s1[4], s1[5]), fmaxf(s1[6], s1[7]));
        float t6 = fmaxf(fmaxf(s1[8], s1[9]), fmaxf(s1[10], s1[11]));
        float t7 = fmaxf(fmaxf(s1[12], s1[13]), fmaxf(s1[14], s1[15]));
        float pmax = fmaxf(fmaxf(fmaxf(t0, t1), fmaxf(t2, t3)),
                           fmaxf(fmaxf(t4, t5), fmaxf(t6, t7)));
        pmax = fmaxf(pmax, __shfl_xor(pmax, 32));

        // defer-max (THR=0, exact); o rescale is lane-local (O^T layout)
        if (!__all(pmax <= m)) {
          const float mnew = fmaxf(m, pmax);
          const float fct = __builtin_amdgcn_exp2f(m - mnew);
          m = mnew;
          l *= fct;
#pragma unroll
          for (int r = 0; r < 16; ++r) { o0[r] *= fct; o1[r] *= fct; }
        }

        // P = exp2(S - m); sum tree + ONE shfl
#pragma unroll
        for (int r = 0; r < 16; ++r) {
          s0[r] = __builtin_amdgcn_exp2f(s0[r] - m);
          s1[r] = __builtin_amdgcn_exp2f(s1[r] - m);
        }
        float u0 = (s0[0] + s0[1]) + (s0[2] + s0[3]);
        float u1 = (s0[4] + s0[5]) + (s0[6] + s0[7]);
        float u2 = (s0[8] + s0[9]) + (s0[10] + s0[11]);
        float u3 = (s0[12] + s0[13]) + (s0[14] + s0[15]);
        float u4 = (s1[0] + s1[1]) + (s1[2] + s1[3]);
        float u5 = (s1[4] + s1[5]) + (s1[6] + s1[7]);
        float u6 = (s1[8] + s1[9]) + (s1[10] + s1[11]);
        float u7 = (s1[12] + s1[13]) + (s1[14] + s1[15]);
        float psum = ((u0 + u1) + (u2 + u3)) + ((u4 + u5) + (u6 + u7));
        psum += __shfl_xor(psum, 32);
        l += psum;

        // pack P -> PV B-operands in NAMED registers (no arrays/unions)
        unsigned pA0 = cvtpk(s0[0], s0[1]), pA1 = cvtpk(s0[2], s0[3]);
        unsigned pA2 = cvtpk(s0[4], s0[5]), pA3 = cvtpk(s0[6], s0[7]);
        unsigned pB0 = cvtpk(s0[8], s0[9]), pB1 = cvtpk(s0[10], s0[11]);
        unsigned pB2 = cvtpk(s0[12], s0[13]), pB3 = cvtpk(s0[14], s0[15]);
        plswap(pA0, pA2); plswap(pA1, pA3); plswap(pB0, pB2); plswap(pB1, pB3);
        unsigned pC0 = cvtpk(s1[0], s1[1]), pC1 = cvtpk(s1[2], s1[3]);
        unsigned pC2 = cvtpk(s1[4], s1[5]), pC3 = cvtpk(s1[6], s1[7]);
        unsigned pD0 = cvtpk(s1[8], s1[9]), pD1 = cvtpk(s1[10], s1[11]);
        unsigned pD2 = cvtpk(s1[12], s1[13]), pD3 = cvtpk(s1[14], s1[15]);
        plswap(pC0, pC2); plswap(pC1, pC3); plswap(pD0, pD2); plswap(pD1, pD3);
        const bf16x8 pbA = __builtin_bit_cast(bf16x8, (u32x4){pA0, pA1, pA2, pA3});
        const bf16x8 pbB = __builtin_bit_cast(bf16x8, (u32x4){pB0, pB1, pB2, pB3});
        const bf16x8 pbC = __builtin_bit_cast(bf16x8, (u32x4){pC0, pC1, pC2, pC3});
        const bf16x8 pbD = __builtin_bit_cast(bf16x8, (u32x4){pD0, pD1, pD2, pD3});

        // O^T += V^T P^T: A = V-frag (rows d), B = P-frag; 8 MFMA
        __builtin_amdgcn_s_setprio(1);
#define PV_STEP(KK, PB)                                                         \
        {                                                                       \
          const int cb = (KK * 32 + h5 * 16);                                   \
          bf16x8 vf0 = *(const bf16x8*)(Vc + l31 * 128 + (cb ^ ((l31 & 7) << 4))); \
          bf16x8 vf1 = *(const bf16x8*)(Vc + (32 + l31) * 128 + (cb ^ ((l31 & 7) << 4))); \
          o0 = __builtin_amdgcn_mfma_f32_32x32x16_bf16(vf0, PB, o0, 0, 0, 0);   \
          o1 = __builtin_amdgcn_mfma_f32_32x32x16_bf16(vf1, PB, o1, 0, 0, 0);   \
        }
        PV_STEP(0, pbA)
        PV_STEP(1, pbB)
        PV_STEP(2, pbC)
        PV_STEP(3, pbD)
#undef PV_STEP
        __builtin_amdgcn_s_setprio(0);
      }
    }

    // epilogue: normalize (lane-local), bounce O^T -> row-major via freed lK,
    // write l-normalized bf16 partial + (m,l)
    __syncthreads();  // all waves done reading lK/lV this pass
    const float li = (l > 0.f) ? __builtin_amdgcn_rcpf(l) : 0.f;
    char* bnc = (char*)lK + w * 4096;  // per-wave 4KB: 32 q-rows x 128B
#pragma unroll
    for (int rg = 0; rg < 4; ++rg) {
      u16x4 pk4;
      pk4[0] = f2bf(o0[rg * 4 + 0] * li); pk4[1] = f2bf(o0[rg * 4 + 1] * li);
      pk4[2] = f2bf(o0[rg * 4 + 2] * li); pk4[3] = f2bf(o0[rg * 4 + 3] * li);
      *(u16x4*)(bnc + l31 * 128 + 0 * 64 + rg * 16 + h5 * 8) = pk4;
    }
#pragma unroll
    for (int rg = 0; rg < 4; ++rg) {
      u16x4 pk4;
      pk4[0] = f2bf(o1[rg * 4 + 0] * li); pk4[1] = f2bf(o1[rg * 4 + 1] * li);
      pk4[2] = f2bf(o1[rg * 4 + 2] * li); pk4[3] = f2bf(o1[rg * 4 + 3] * li);
      *(u16x4*)(bnc + l31 * 128 + 1 * 64 + rg * 16 + h5 * 8) = pk4;
    }
    // same-wave readback (DS in-order): row l31, half h5 -> coalesced po write
#pragma unroll
    for (int j = 0; j < 4; ++j) {
      u16x8 vv = *(const u16x8*)(bnc + l31 * 128 + h5 * 64 + j * 16);
      *(u16x8*)&pob[((size_t)b * T + q0 + w * 32 + l31) * 1024 + h * 64 + h5 * 32 + j * 8] = vv;
    }
    if (h5 == 0) {
      float* mp = mlf + (size_t)tr * 131072ull + ((size_t)(b * T + qrow) * 16 + h) * 2;
      mp[0] = m;
      mp[1] = l;
    }
  }
}

// ---------------- merge the three kv-thirds ----------------
__global__ __launch_bounds__(256) void merge3(const u16* __restrict__ p0,
                                              const u16* __restrict__ p1,
                                              const u16* __restrict__ p2,
                                              const float* __restrict__ mlf,
                                              u16* __restrict__ y) {
  const int gid = blockIdx.x * 256 + threadIdx.x;   // 524288 threads
  const int row = gid >> 3, d0 = (gid & 7) * 8;     // row in [0, 65536)
  const int bt = row >> 4, hh = row & 15;
  const float m1 = mlf[row * 2], l1 = mlf[row * 2 + 1];
  const float m2 = mlf[131072 + row * 2], l2 = mlf[131072 + row * 2 + 1];
  const float m3 = mlf[262144 + row * 2], l3 = mlf[262144 + row * 2 + 1];
  const float ms = fmaxf(fmaxf(m1, m2), m3);
  const float a1 = l1 * __builtin_amdgcn_exp2f(m1 - ms);
  const float a2 = l2 * __builtin_amdgcn_exp2f(m2 - ms);
  const float a3 = l3 * __builtin_amdgcn_exp2f(m3 - ms);
  const float inv = __builtin_amdgcn_rcpf(a1 + a2 + a3);
  const float w1 = a1 * inv, w2 = a2 * inv, w3 = a3 * inv;
  const size_t off = (size_t)bt * 1024 + hh * 64 + d0;
  u16x8 q1 = *(const u16x8*)&p0[off];
  u16x8 q2 = *(const u16x8*)&p1[off];
  u16x8 q3 = *(const u16x8*)&p2[off];
  u16x8 o;
#pragma unroll
  for (int j = 0; j < 8; ++j)
    o[j] = f2bf(w1 * bf2f(q1[j]) + w2 * bf2f(q2[j]) + w3 * bf2f(q3[j]));
  *(u16x8*)&y[off] = o;
}

extern "C" void kernel_launch(void* const* d_in, const int* in_sizes, int n_in,
                              void* d_out, int out_size, void* d_ws, size_t ws_size,
                              hipStream_t stream) {
  const float* x = (const float*)d_in[0];
  const float* Wqkv = (const float*)d_in[1];
  const float* Wproj = (const float*)d_in[2];
  float* out = (float*)d_out;

  constexpr int B = 2, T = 2048, C = 1024, C3 = 3072, H = 16, D = 64;
  constexpr int M = B * T;  // 4096

  u16* xb = (u16*)d_ws;                       // M*C   (dead after qkv GEMM -> po slice 2)
  u16* wqkvb = xb + (size_t)M * C;            // C3*C
  u16* wprojb = wqkvb + (size_t)C3 * C;       // C*C
  u16* qkvb = wprojb + (size_t)C * C;         // M*C3 (v-part unused)
  u16* vtb = qkvb + (size_t)M * C3;           // B*H*D*T = M*C
  u16* yb = vtb + (size_t)M * C;              // M*C
  u16* po = yb + (size_t)M * C;               // 2 * M*C (slices 0,1)
  float* mlf = (float*)(po + 2ull * M * C);   // 3 * 65536 * 2 floats
  u16* po2 = xb;                              // slice 2 aliases dead xb

  constexpr int n1 = (M * C) / 4, n2 = (C3 * C) / 4, n3 = (C * C) / 4;
  cvt3_f32_bf16<<<dim3((n1 + n2 + n3 + 255) / 256), 256, 0, stream>>>(
      x, Wqkv, Wproj, xb, n1, n2, n3);

  gemm_nt<1, 1><<<dim3((C3 / 128) * (M / 128)), 256, 0, stream>>>(
      xb, wqkvb, qkvb, vtb, M, C3, C, M / 128);
  attn_fwd<<<dim3(768), 256, 0, stream>>>(qkvb, vtb, po, po + (size_t)M * C, po2, mlf);
  merge3<<<dim3(2048), 256, 0, stream>>>(po, po + (size_t)M * C, po2, mlf, yb);
  gemm_nt<0, 0><<<dim3((C / 128) * (M / 128)), 256, 0, stream>>>(
      yb, wprojb, out, nullptr, M, C, C, M / 128);
}

// Round 21
// 120.488 us; speedup vs baseline: 2.2094x; 1.0224x over previous
//
#include <hip/hip_runtime.h>

typedef unsigned short u16;
typedef float f32x4 __attribute__((ext_vector_type(4)));
typedef __bf16 bf16x8 __attribute__((ext_vector_type(8)));
typedef unsigned int u32x4 __attribute__((ext_vector_type(4)));
typedef u16 u16x4 __attribute__((ext_vector_type(4)));
typedef u16 u16x8 __attribute__((ext_vector_type(8)));

static __device__ __forceinline__ u16 f2bf(float f) {
  union { __bf16 h; u16 u; } c;
  c.h = (__bf16)f;
  return c.u;
}
static __device__ __forceinline__ float bf2f(u16 u) {
  union { unsigned u; float f; } c;
  c.u = ((unsigned)u) << 16;
  return c.f;
}

static __device__ __forceinline__ void gload_lds16(const void* g, void* l) {
  __builtin_amdgcn_global_load_lds(
      (const __attribute__((address_space(1))) unsigned int*)g,
      (__attribute__((address_space(3))) unsigned int*)l, 16, 0, 0);
}

// ---------------- fused fp32 -> bf16 convert ----------------
__global__ __launch_bounds__(256) void cvt3_f32_bf16(const float* __restrict__ a,
                                                     const float* __restrict__ bb,
                                                     const float* __restrict__ cc,
                                                     u16* __restrict__ out,
                                                     int n1, int n2, int n3) {
  int i = blockIdx.x * 256 + threadIdx.x;
  const float* src;
  int j = i;
  if (i < n1) { src = a; }
  else if (i < n1 + n2) { src = bb; j = i - n1; }
  else { src = cc; j = i - n1 - n2; if (j >= n3) return; }
  f32x4 v = *((const f32x4*)src + j);
  u16x4 o;
  o[0] = f2bf(v[0]); o[1] = f2bf(v[1]); o[2] = f2bf(v[2]); o[3] = f2bf(v[3]);
  *((u16x4*)out + i) = o;
}

// ---------------- 128x128 GEMM (proven m97-structure) ----------------
// XCD-aware 1D decode. FUSE_VT: v-panels (bn>=2048) write vt[bh][d][t] directly.
template<int OUT_BF16, int FUSE_VT>
__global__ __launch_bounds__(256) void gemm_nt(const u16* __restrict__ A,
                                               const u16* __restrict__ B,
                                               void* __restrict__ Cp,
                                               u16* __restrict__ vt,
                                               int M, int N, int K, int gy) {
  __shared__ __align__(16) u16 lA[128 * 64];
  __shared__ __align__(16) u16 lB[128 * 64];
  const int tid = threadIdx.x;
  const int lane = tid & 63;
  const int wave = tid >> 6;
  const int wm = wave >> 1, wn = wave & 1;
  const int l15 = lane & 15, lg = lane >> 4;

  const int bid = blockIdx.x;
  const int xcd = bid & 7, s = bid >> 3;
  const int pnx = (N >> 7) >> 3;
  const int bm = (s % gy) * 128;
  const int bn = (xcd * pnx + s / gy) * 128;

  f32x4 acc[4][4];
#pragma unroll
  for (int i = 0; i < 4; ++i)
#pragma unroll
    for (int j = 0; j < 4; ++j) acc[i][j] = (f32x4){0.f, 0.f, 0.f, 0.f};

  const u16* Ag[4];
  const u16* Bg[4];
#pragma unroll
  for (int it = 0; it < 4; ++it) {
    const int ss = it * 256 + tid;
    const int row = ss >> 3, g = ss & 7;
    const int gsw = g ^ (row & 7);
    Ag[it] = A + (size_t)(bm + row) * K + gsw * 8;
    Bg[it] = B + (size_t)(bn + row) * K + gsw * 8;
  }

  for (int k0 = 0; k0 < K; k0 += 64) {
#pragma unroll
    for (int it = 0; it < 4; ++it) {
      gload_lds16(Ag[it] + k0, (u16*)lA + (size_t)(it * 256 + tid) * 8);
      gload_lds16(Bg[it] + k0, (u16*)lB + (size_t)(it * 256 + tid) * 8);
    }
    __syncthreads();
#pragma unroll
    for (int kk = 0; kk < 2; ++kk) {
      bf16x8 af[4], bfv[4];
#pragma unroll
      for (int mf = 0; mf < 4; ++mf) {
        const int row = wm * 64 + mf * 16 + l15;
        af[mf] = *(const bf16x8*)((const char*)lA + row * 128 +
                                  ((kk * 64 + lg * 16) ^ ((row & 7) << 4)));
      }
#pragma unroll
      for (int nf = 0; nf < 4; ++nf) {
        const int row = wn * 64 + nf * 16 + l15;
        bfv[nf] = *(const bf16x8*)((const char*)lB + row * 128 +
                                   ((kk * 64 + lg * 16) ^ ((row & 7) << 4)));
      }
#pragma unroll
      for (int mf = 0; mf < 4; ++mf)
#pragma unroll
        for (int nf = 0; nf < 4; ++nf)
          acc[mf][nf] = __builtin_amdgcn_mfma_f32_16x16x32_bf16(af[mf], bfv[nf], acc[mf][nf], 0, 0, 0);
    }
    __syncthreads();
  }

  if (FUSE_VT && bn >= 2048) {
#pragma unroll
    for (int mf = 0; mf < 4; ++mf) {
      const int row0 = bm + wm * 64 + mf * 16 + lg * 4;
      const int b = row0 >> 11, t0 = row0 & 2047;
#pragma unroll
      for (int nf = 0; nf < 4; ++nf) {
        const int colv = bn - 2048 + wn * 64 + nf * 16 + l15;
        const int h = colv >> 6, d = colv & 63;
        u16x4 pk;
        pk[0] = f2bf(acc[mf][nf][0]); pk[1] = f2bf(acc[mf][nf][1]);
        pk[2] = f2bf(acc[mf][nf][2]); pk[3] = f2bf(acc[mf][nf][3]);
        *(u16x4*)&vt[((size_t)((b * 16 + h) * 64 + d)) * 2048 + t0] = pk;
      }
    }
  } else {
#pragma unroll
    for (int mf = 0; mf < 4; ++mf) {
#pragma unroll
      for (int r = 0; r < 4; ++r) {
        const int row = bm + wm * 64 + mf * 16 + lg * 4 + r;
#pragma unroll
        for (int nf = 0; nf < 4; ++nf) {
          const int col = bn + wn * 64 + nf * 16 + l15;
          const float v = acc[mf][nf][r];
          if (OUT_BF16) ((u16*)Cp)[(size_t)row * N + col] = f2bf(v);
          else          ((float*)Cp)[(size_t)row * N + col] = v;
        }
      }
    }
  }
}

// ---------------- flash attention fwd (causal), QBLK=128 / 8 waves, kv-THIRDS ----------------
// R15 champion body (44.4us @ halves). Block (bh, pi, tr): q-passes qt=pi and
// qt=15-pi, kv-THIRD tr of each -> 10-12 iters/block (balanced). 768 blocks x
// 8 waves = 3 blocks/CU (144KB LDS), 24 waves/CU. Partial O (l-normalized bf16)
// + (m,l); merge3 combines. nit==0 passes yield zero-weight partials.
__global__ __launch_bounds__(512) void attn_fwd(const u16* __restrict__ qkv,
                                                const u16* __restrict__ vt,
                                                u16* __restrict__ po0,
                                                u16* __restrict__ po1,
                                                u16* __restrict__ po2,
                                                float* __restrict__ mlf) {
  constexpr int T = 2048, C = 1024, C3 = 3072;
  __shared__ __align__(16) u16 lK[2][64 * 64];
  __shared__ __align__(16) u16 lV[2][64 * 64];
  __shared__ __align__(16) u16 lP[8 * 16 * 64];
  const int tid = threadIdx.x, lane = tid & 63, w = tid >> 6;  // w in [0,8)
  const int l15 = lane & 15, lg = lane >> 4;

  // decode: 768 blocks; xcd hosts bh in [4c,4c+4); pi in [0,8); tr in {0,1,2}
  const int bid = blockIdx.x;
  const int xcd = bid & 7, slot = bid >> 3;          // slot in [0,96)
  const int bh = xcd * 4 + slot / 24;
  const int rem = slot % 24;
  const int pi = rem / 3, tr = rem % 3;
  const int b = bh >> 4, h = bh & 15;

  // staging: ONE 16B chunk per thread per tile (512 thr x 16B = 8KB = 64x64 bf16)
  const int r0 = tid >> 3, off0 = (tid & 7) * 8;
  const int sb0 = (off0 * 2) ^ ((r0 & 7) << 4);
  const u16* Kbase = qkv + (size_t)b * T * C3 + C + h * 64;
  const u16* Vbase = vt + (size_t)bh * 64 * T;
  char* lPb = (char*)lP + w * 2048;
  u16* pob = (tr == 0) ? po0 : ((tr == 1) ? po1 : po2);

  const float qscale = 0.125f * 1.44269504088896f;  // scale * log2(e)

#pragma unroll 1
  for (int qi = 0; qi < 2; ++qi) {
    const int qt = (qi == 0) ? pi : (15 - pi);   // 128-row q-tile index
    const int q0 = qt * 128;
    const int nkt = 2 * qt + 2;                  // kv tiles of 64
    const int kts = tr * nkt / 3;
    const int kte = (tr + 1) * nkt / 3;
    const int nit = kte - kts;
    const int qrow = q0 + w * 16 + l15;

    const size_t qoff = ((size_t)b * T + qrow) * C3 + h * 64;
    const bf16x8 aq0 = *(const bf16x8*)&qkv[qoff + lg * 8];
    const bf16x8 aq1 = *(const bf16x8*)&qkv[qoff + 32 + lg * 8];

    float m = -1.0e30f, l = 0.f;
    f32x4 o_acc[4];
#pragma unroll
    for (int nf = 0; nf < 4; ++nf) o_acc[nf] = (f32x4){0.f, 0.f, 0.f, 0.f};

    if (nit > 0) {
      // prologue: tile kts -> regs; drain prev pass readers; -> buf0
      u32x4 rk0 = *(const u32x4*)(Kbase + (size_t)(kts * 64 + r0) * C3 + off0);
      u32x4 rv0 = *(const u32x4*)(Vbase + (size_t)r0 * T + kts * 64 + off0);
      __syncthreads();
      *(u32x4*)&lK[0][(r0 * 128 + sb0) >> 1] = rk0;
      *(u32x4*)&lV[0][(r0 * 128 + sb0) >> 1] = rv0;
      if (nit > 1) {
        rk0 = *(const u32x4*)(Kbase + (size_t)((kts + 1) * 64 + r0) * C3 + off0);
        rv0 = *(const u32x4*)(Vbase + (size_t)r0 * T + (kts + 1) * 64 + off0);
      }

      for (int i = 0; i < nit; ++i) {
        const int kt = kts + i;
        const int cur = i & 1;
        __syncthreads();  // buf[cur] visible; buf[cur^1] readers drained
        if (i < nit - 1) {
          *(u32x4*)&lK[cur ^ 1][(r0 * 128 + sb0) >> 1] = rk0;
          *(u32x4*)&lV[cur ^ 1][(r0 * 128 + sb0) >> 1] = rv0;
          if (i + 1 < nit - 1) {
            const int kn = (kt + 2) * 64;
            rk0 = *(const u32x4*)(Kbase + (size_t)(kn + r0) * C3 + off0);
            rv0 = *(const u32x4*)(Vbase + (size_t)r0 * T + kn + off0);
          }
        }
        const u16* Kc = lK[cur];
        const u16* Vc = lV[cur];

        // S^T = K Q^T (lane owns q-row qrow; s holds kv = kt*64 + nf*16+lg*4+r)
        f32x4 s[4];
#pragma unroll
        for (int nf = 0; nf < 4; ++nf) s[nf] = (f32x4){0.f, 0.f, 0.f, 0.f};
        __builtin_amdgcn_s_setprio(1);
#pragma unroll
        for (int nf = 0; nf < 4; ++nf) {
          const int row = nf * 16 + l15;
          const int x = (row & 7) << 4;
          bf16x8 bk0 = *(const bf16x8*)&Kc[(row * 128 + ((lg * 16) ^ x)) >> 1];
          bf16x8 bk1 = *(const bf16x8*)&Kc[(row * 128 + ((64 + lg * 16) ^ x)) >> 1];
          s[nf] = __builtin_amdgcn_mfma_f32_16x16x32_bf16(bk0, aq0, s[nf], 0, 0, 0);
          s[nf] = __builtin_amdgcn_mfma_f32_16x16x32_bf16(bk1, aq1, s[nf], 0, 0, 0);
        }
        __builtin_amdgcn_s_setprio(0);

        // scale (+ causal mask only when tile can cross the diagonal)
        if (kt >= 2 * qt) {
          const int kb = kt * 64;
#pragma unroll
          for (int nf = 0; nf < 4; ++nf)
#pragma unroll
            for (int r = 0; r < 4; ++r) {
              float v = s[nf][r] * qscale;
              if (kb + nf * 16 + lg * 4 + r > qrow) v = -1.0e30f;
              s[nf][r] = v;
            }
        } else {
#pragma unroll
          for (int nf = 0; nf < 4; ++nf)
#pragma unroll
            for (int r = 0; r < 4; ++r) s[nf][r] *= qscale;
        }

        float t0a = fmaxf(fmaxf(s[0][0], s[0][1]), fmaxf(s[0][2], s[0][3]));
        float t1a = fmaxf(fmaxf(s[1][0], s[1][1]), fmaxf(s[1][2], s[1][3]));
        float t2a = fmaxf(fmaxf(s[2][0], s[2][1]), fmaxf(s[2][2], s[2][3]));
        float t3a = fmaxf(fmaxf(s[3][0], s[3][1]), fmaxf(s[3][2], s[3][3]));
        float pmax = fmaxf(fmaxf(t0a, t1a), fmaxf(t2a, t3a));
        pmax = fmaxf(pmax, __shfl_xor(pmax, 16));
        pmax = fmaxf(pmax, __shfl_xor(pmax, 32));

        if (!__all(pmax <= m)) {
          const float mnew = fmaxf(m, pmax);
          const float fct = __builtin_amdgcn_exp2f(m - mnew);
          m = mnew;
          l *= fct;
#pragma unroll
          for (int r = 0; r < 4; ++r) {
            const float fr = __shfl(fct, lg * 4 + r);
#pragma unroll
            for (int nf = 0; nf < 4; ++nf) o_acc[nf][r] *= fr;
          }
        }

        float p[4][4];
#pragma unroll
        for (int nf = 0; nf < 4; ++nf)
#pragma unroll
          for (int r = 0; r < 4; ++r) p[nf][r] = __builtin_amdgcn_exp2f(s[nf][r] - m);
        float s0a = (p[0][0] + p[0][1]) + (p[0][2] + p[0][3]);
        float s1a = (p[1][0] + p[1][1]) + (p[1][2] + p[1][3]);
        float s2a = (p[2][0] + p[2][1]) + (p[2][2] + p[2][3]);
        float s3a = (p[3][0] + p[3][1]) + (p[3][2] + p[3][3]);
        float psum = (s0a + s1a) + (s2a + s3a);
        psum += __shfl_xor(psum, 16);
        psum += __shfl_xor(psum, 32);
        l += psum;

        // P -> per-wave LDS region (packed b64, swizzled); same-wave RAW
#pragma unroll
        for (int nf = 0; nf < 4; ++nf) {
          u16x4 pk;
          pk[0] = f2bf(p[nf][0]); pk[1] = f2bf(p[nf][1]);
          pk[2] = f2bf(p[nf][2]); pk[3] = f2bf(p[nf][3]);
          *(u16x4*)(lPb + l15 * 128 + ((nf * 32 + lg * 8) ^ ((l15 & 7) << 4))) = pk;
        }

        // O += P V
        __builtin_amdgcn_s_setprio(1);
#pragma unroll
        for (int sj = 0; sj < 2; ++sj) {
          bf16x8 ap = *(const bf16x8*)(lPb + l15 * 128 + ((sj * 64 + lg * 16) ^ ((l15 & 7) << 4)));
#pragma unroll
          for (int nf = 0; nf < 4; ++nf) {
            const int d = nf * 16 + l15;
            bf16x8 bv = *(const bf16x8*)&Vc[(d * 128 + ((sj * 64 + lg * 16) ^ ((d & 7) << 4))) >> 1];
            o_acc[nf] = __builtin_amdgcn_mfma_f32_16x16x32_bf16(ap, bv, o_acc[nf], 0, 0, 0);
          }
        }
        __builtin_amdgcn_s_setprio(0);
      }
    }

    // epilogue: l-normalized bf16 partial O + (m,l)
#pragma unroll
    for (int r = 0; r < 4; ++r) {
      const float lv = __shfl(l, lg * 4 + r);
      const float li = (lv > 0.f) ? __builtin_amdgcn_rcpf(lv) : 0.f;
      const int row = q0 + w * 16 + lg * 4 + r;
#pragma unroll
      for (int nf = 0; nf < 4; ++nf) {
        const int col = h * 64 + nf * 16 + l15;
        pob[((size_t)b * T + row) * C + col] = f2bf(o_acc[nf][r] * li);
      }
    }
    if (lg == 0) {
      float* mp = mlf + (size_t)tr * 131072ull + ((size_t)(b * T + qrow) * 16 + h) * 2;
      mp[0] = m;
      mp[1] = l;
    }
  }
}

// ---------------- merge the three kv-thirds ----------------
__global__ __launch_bounds__(256) void merge3(const u16* __restrict__ p0,
                                              const u16* __restrict__ p1,
                                              const u16* __restrict__ p2,
                                              const float* __restrict__ mlf,
                                              u16* __restrict__ y) {
  const int gid = blockIdx.x * 256 + threadIdx.x;   // 524288 threads
  const int row = gid >> 3, d0 = (gid & 7) * 8;     // row in [0, 65536)
  const int bt = row >> 4, hh = row & 15;
  const float m1 = mlf[row * 2], l1 = mlf[row * 2 + 1];
  const float m2 = mlf[131072 + row * 2], l2 = mlf[131072 + row * 2 + 1];
  const float m3 = mlf[262144 + row * 2], l3 = mlf[262144 + row * 2 + 1];
  const float ms = fmaxf(fmaxf(m1, m2), m3);
  const float a1 = l1 * __builtin_amdgcn_exp2f(m1 - ms);
  const float a2 = l2 * __builtin_amdgcn_exp2f(m2 - ms);
  const float a3 = l3 * __builtin_amdgcn_exp2f(m3 - ms);
  const float inv = __builtin_amdgcn_rcpf(a1 + a2 + a3);
  const float w1 = a1 * inv, w2 = a2 * inv, w3 = a3 * inv;
  const size_t off = (size_t)bt * 1024 + hh * 64 + d0;
  u16x8 q1 = *(const u16x8*)&p0[off];
  u16x8 q2 = *(const u16x8*)&p1[off];
  u16x8 q3 = *(const u16x8*)&p2[off];
  u16x8 o;
#pragma unroll
  for (int j = 0; j < 8; ++j)
    o[j] = f2bf(w1 * bf2f(q1[j]) + w2 * bf2f(q2[j]) + w3 * bf2f(q3[j]));
  *(u16x8*)&y[off] = o;
}

extern "C" void kernel_launch(void* const* d_in, const int* in_sizes, int n_in,
                              void* d_out, int out_size, void* d_ws, size_t ws_size,
                              hipStream_t stream) {
  const float* x = (const float*)d_in[0];
  const float* Wqkv = (const float*)d_in[1];
  const float* Wproj = (const float*)d_in[2];
  float* out = (float*)d_out;

  constexpr int B = 2, T = 2048, C = 1024, C3 = 3072, H = 16, D = 64;
  constexpr int M = B * T;  // 4096

  u16* xb = (u16*)d_ws;                       // M*C (dead after qkv GEMM -> po slice 2)
  u16* wqkvb = xb + (size_t)M * C;            // C3*C
  u16* wprojb = wqkvb + (size_t)C3 * C;       // C*C
  u16* qkvb = wprojb + (size_t)C * C;         // M*C3 (v-part unused)
  u16* vtb = qkvb + (size_t)M * C3;           // B*H*D*T = M*C
  u16* yb = vtb + (size_t)M * C;              // M*C
  u16* po = yb + (size_t)M * C;               // 2 * M*C (slices 0,1)
  float* mlf = (float*)(po + 2ull * M * C);   // 3 * 65536 * 2 floats
  u16* po2 = xb;                              // slice 2 aliases dead xb

  constexpr int n1 = (M * C) / 4, n2 = (C3 * C) / 4, n3 = (C * C) / 4;
  cvt3_f32_bf16<<<dim3((n1 + n2 + n3 + 255) / 256), 256, 0, stream>>>(
      x, Wqkv, Wproj, xb, n1, n2, n3);

  gemm_nt<1, 1><<<dim3((C3 / 128) * (M / 128)), 256, 0, stream>>>(
      xb, wqkvb, qkvb, vtb, M, C3, C, M / 128);
  attn_fwd<<<dim3(768), 512, 0, stream>>>(qkvb, vtb, po, po + (size_t)M * C, po2, mlf);
  merge3<<<dim3(2048), 256, 0, stream>>>(po, po + (size_t)M * C, po2, mlf, yb);
  gemm_nt<0, 0><<<dim3((C / 128) * (M / 128)), 256, 0, stream>>>(
      yb, wprojb, out, nullptr, M, C, C, M / 128);
}

// Round 22
// 110.763 us; speedup vs baseline: 2.4034x; 1.0878x over previous
//
#include <hip/hip_runtime.h>

typedef unsigned short u16;
typedef float f32x4 __attribute__((ext_vector_type(4)));
typedef __bf16 bf16x8 __attribute__((ext_vector_type(8)));
typedef unsigned int u32x4 __attribute__((ext_vector_type(4)));
typedef u16 u16x4 __attribute__((ext_vector_type(4)));
typedef u16 u16x8 __attribute__((ext_vector_type(8)));

static __device__ __forceinline__ u16 f2bf(float f) {
  union { __bf16 h; u16 u; } c;
  c.h = (__bf16)f;
  return c.u;
}
static __device__ __forceinline__ float bf2f(u16 u) {
  union { unsigned u; float f; } c;
  c.u = ((unsigned)u) << 16;
  return c.f;
}

static __device__ __forceinline__ void gload_lds16(const void* g, void* l) {
  __builtin_amdgcn_global_load_lds(
      (const __attribute__((address_space(1))) unsigned int*)g,
      (__attribute__((address_space(3))) unsigned int*)l, 16, 0, 0);
}

// ---------------- fused fp32 -> bf16 convert ----------------
__global__ __launch_bounds__(256) void cvt3_f32_bf16(const float* __restrict__ a,
                                                     const float* __restrict__ bb,
                                                     const float* __restrict__ cc,
                                                     u16* __restrict__ out,
                                                     int n1, int n2, int n3) {
  int i = blockIdx.x * 256 + threadIdx.x;
  const float* src;
  int j = i;
  if (i < n1) { src = a; }
  else if (i < n1 + n2) { src = bb; j = i - n1; }
  else { src = cc; j = i - n1 - n2; if (j >= n3) return; }
  f32x4 v = *((const f32x4*)src + j);
  u16x4 o;
  o[0] = f2bf(v[0]); o[1] = f2bf(v[1]); o[2] = f2bf(v[2]); o[3] = f2bf(v[3]);
  *((u16x4*)out + i) = o;
}

// ---------------- 128x128 GEMM (proven m97-structure) ----------------
// XCD-aware 1D decode. FUSE_VT: v-panels (bn>=2048) write vt[bh][d][t] directly.
template<int OUT_BF16, int FUSE_VT>
__global__ __launch_bounds__(256) void gemm_nt(const u16* __restrict__ A,
                                               const u16* __restrict__ B,
                                               void* __restrict__ Cp,
                                               u16* __restrict__ vt,
                                               int M, int N, int K, int gy) {
  __shared__ __align__(16) u16 lA[128 * 64];
  __shared__ __align__(16) u16 lB[128 * 64];
  const int tid = threadIdx.x;
  const int lane = tid & 63;
  const int wave = tid >> 6;
  const int wm = wave >> 1, wn = wave & 1;
  const int l15 = lane & 15, lg = lane >> 4;

  const int bid = blockIdx.x;
  const int xcd = bid & 7, s = bid >> 3;
  const int pnx = (N >> 7) >> 3;
  const int bm = (s % gy) * 128;
  const int bn = (xcd * pnx + s / gy) * 128;

  f32x4 acc[4][4];
#pragma unroll
  for (int i = 0; i < 4; ++i)
#pragma unroll
    for (int j = 0; j < 4; ++j) acc[i][j] = (f32x4){0.f, 0.f, 0.f, 0.f};

  const u16* Ag[4];
  const u16* Bg[4];
#pragma unroll
  for (int it = 0; it < 4; ++it) {
    const int ss = it * 256 + tid;
    const int row = ss >> 3, g = ss & 7;
    const int gsw = g ^ (row & 7);
    Ag[it] = A + (size_t)(bm + row) * K + gsw * 8;
    Bg[it] = B + (size_t)(bn + row) * K + gsw * 8;
  }

  for (int k0 = 0; k0 < K; k0 += 64) {
#pragma unroll
    for (int it = 0; it < 4; ++it) {
      gload_lds16(Ag[it] + k0, (u16*)lA + (size_t)(it * 256 + tid) * 8);
      gload_lds16(Bg[it] + k0, (u16*)lB + (size_t)(it * 256 + tid) * 8);
    }
    __syncthreads();
#pragma unroll
    for (int kk = 0; kk < 2; ++kk) {
      bf16x8 af[4], bfv[4];
#pragma unroll
      for (int mf = 0; mf < 4; ++mf) {
        const int row = wm * 64 + mf * 16 + l15;
        af[mf] = *(const bf16x8*)((const char*)lA + row * 128 +
                                  ((kk * 64 + lg * 16) ^ ((row & 7) << 4)));
      }
#pragma unroll
      for (int nf = 0; nf < 4; ++nf) {
        const int row = wn * 64 + nf * 16 + l15;
        bfv[nf] = *(const bf16x8*)((const char*)lB + row * 128 +
                                   ((kk * 64 + lg * 16) ^ ((row & 7) << 4)));
      }
#pragma unroll
      for (int mf = 0; mf < 4; ++mf)
#pragma unroll
        for (int nf = 0; nf < 4; ++nf)
          acc[mf][nf] = __builtin_amdgcn_mfma_f32_16x16x32_bf16(af[mf], bfv[nf], acc[mf][nf], 0, 0, 0);
    }
    __syncthreads();
  }

  if (FUSE_VT && bn >= 2048) {
#pragma unroll
    for (int mf = 0; mf < 4; ++mf) {
      const int row0 = bm + wm * 64 + mf * 16 + lg * 4;
      const int b = row0 >> 11, t0 = row0 & 2047;
#pragma unroll
      for (int nf = 0; nf < 4; ++nf) {
        const int colv = bn - 2048 + wn * 64 + nf * 16 + l15;
        const int h = colv >> 6, d = colv & 63;
        u16x4 pk;
        pk[0] = f2bf(acc[mf][nf][0]); pk[1] = f2bf(acc[mf][nf][1]);
        pk[2] = f2bf(acc[mf][nf][2]); pk[3] = f2bf(acc[mf][nf][3]);
        *(u16x4*)&vt[((size_t)((b * 16 + h) * 64 + d)) * 2048 + t0] = pk;
      }
    }
  } else {
#pragma unroll
    for (int mf = 0; mf < 4; ++mf) {
#pragma unroll
      for (int r = 0; r < 4; ++r) {
        const int row = bm + wm * 64 + mf * 16 + lg * 4 + r;
#pragma unroll
        for (int nf = 0; nf < 4; ++nf) {
          const int col = bn + wn * 64 + nf * 16 + l15;
          const float v = acc[mf][nf][r];
          if (OUT_BF16) ((u16*)Cp)[(size_t)row * N + col] = f2bf(v);
          else          ((float*)Cp)[(size_t)row * N + col] = v;
        }
      }
    }
  }
}

// ---------------- flash attention fwd (causal), QBLK=128 / 8 waves, kv-split ----------------
// R15 champion: block (bh, pi, hf) does q-passes qt=pi and qt=15-pi, kv-half hf
// of each -> (pi+1)+(16-pi) = 17 iters for EVERY block. 512 blocks x 8 waves =
// 2 blocks/CU, uniform lifetimes. Writes l-normalized bf16 partial O + (m,l);
// merge_o combines the two halves.
__global__ __launch_bounds__(512) void attn_fwd(const u16* __restrict__ qkv,
                                                const u16* __restrict__ vt,
                                                u16* __restrict__ po,
                                                float* __restrict__ mlf) {
  constexpr int T = 2048, C = 1024, C3 = 3072;
  __shared__ __align__(16) u16 lK[2][64 * 64];
  __shared__ __align__(16) u16 lV[2][64 * 64];
  __shared__ __align__(16) u16 lP[8 * 16 * 64];
  const int tid = threadIdx.x, lane = tid & 63, w = tid >> 6;  // w in [0,8)
  const int l15 = lane & 15, lg = lane >> 4;

  // decode: 512 blocks; xcd hosts bh in [4c,4c+4); pi in [0,8); hf in {0,1}
  const int bid = blockIdx.x;
  const int xcd = bid & 7, slot = bid >> 3;          // slot in [0,64)
  const int bh = xcd * 4 + (slot >> 4);
  const int rem = slot & 15;
  const int pi = rem >> 1, hf = rem & 1;
  const int b = bh >> 4, h = bh & 15;

  // staging: ONE 16B chunk per thread per tile
  const int r0 = tid >> 3, off0 = (tid & 7) * 8;
  const int sb0 = (off0 * 2) ^ ((r0 & 7) << 4);
  const u16* Kbase = qkv + (size_t)b * T * C3 + C + h * 64;
  const u16* Vbase = vt + (size_t)bh * 64 * T;
  char* lPb = (char*)lP + w * 2048;

  const float qscale = 0.125f * 1.44269504088896f;  // scale * log2(e)

#pragma unroll 1
  for (int qi = 0; qi < 2; ++qi) {
    const int qt = (qi == 0) ? pi : (15 - pi);   // 128-row q-tile index
    const int q0 = qt * 128;
    const int kts = hf ? (qt + 1) : 0;           // kv-half ranges, each qt+1 tiles
    const int kte = hf ? (2 * qt + 2) : (qt + 1);
    const int nit = kte - kts;
    const int qrow = q0 + w * 16 + l15;

    const size_t qoff = ((size_t)b * T + qrow) * C3 + h * 64;
    const bf16x8 aq0 = *(const bf16x8*)&qkv[qoff + lg * 8];
    const bf16x8 aq1 = *(const bf16x8*)&qkv[qoff + 32 + lg * 8];

    float m = -1.0e30f, l = 0.f;
    f32x4 o_acc[4];
#pragma unroll
    for (int nf = 0; nf < 4; ++nf) o_acc[nf] = (f32x4){0.f, 0.f, 0.f, 0.f};

    // prologue: tile kts -> regs; drain prev pass readers; -> buf0
    u32x4 rk0 = *(const u32x4*)(Kbase + (size_t)(kts * 64 + r0) * C3 + off0);
    u32x4 rv0 = *(const u32x4*)(Vbase + (size_t)r0 * T + kts * 64 + off0);
    __syncthreads();
    *(u32x4*)&lK[0][(r0 * 128 + sb0) >> 1] = rk0;
    *(u32x4*)&lV[0][(r0 * 128 + sb0) >> 1] = rv0;
    if (nit > 1) {
      rk0 = *(const u32x4*)(Kbase + (size_t)((kts + 1) * 64 + r0) * C3 + off0);
      rv0 = *(const u32x4*)(Vbase + (size_t)r0 * T + (kts + 1) * 64 + off0);
    }

    for (int i = 0; i < nit; ++i) {
      const int kt = kts + i;
      const int cur = i & 1;
      __syncthreads();  // buf[cur] visible; buf[cur^1] readers drained
      if (i < nit - 1) {
        *(u32x4*)&lK[cur ^ 1][(r0 * 128 + sb0) >> 1] = rk0;
        *(u32x4*)&lV[cur ^ 1][(r0 * 128 + sb0) >> 1] = rv0;
        if (i + 1 < nit - 1) {
          const int kn = (kt + 2) * 64;
          rk0 = *(const u32x4*)(Kbase + (size_t)(kn + r0) * C3 + off0);
          rv0 = *(const u32x4*)(Vbase + (size_t)r0 * T + kn + off0);
        }
      }
      const u16* Kc = lK[cur];
      const u16* Vc = lV[cur];

      // S^T = K Q^T (lane owns q-row qrow; s holds kv = kt*64 + nf*16+lg*4+r)
      f32x4 s[4];
#pragma unroll
      for (int nf = 0; nf < 4; ++nf) s[nf] = (f32x4){0.f, 0.f, 0.f, 0.f};
      __builtin_amdgcn_s_setprio(1);
#pragma unroll
      for (int nf = 0; nf < 4; ++nf) {
        const int row = nf * 16 + l15;
        const int x = (row & 7) << 4;
        bf16x8 bk0 = *(const bf16x8*)&Kc[(row * 128 + ((lg * 16) ^ x)) >> 1];
        bf16x8 bk1 = *(const bf16x8*)&Kc[(row * 128 + ((64 + lg * 16) ^ x)) >> 1];
        s[nf] = __builtin_amdgcn_mfma_f32_16x16x32_bf16(bk0, aq0, s[nf], 0, 0, 0);
        s[nf] = __builtin_amdgcn_mfma_f32_16x16x32_bf16(bk1, aq1, s[nf], 0, 0, 0);
      }
      __builtin_amdgcn_s_setprio(0);

      // scale (+ causal mask only when tile can cross the diagonal)
      if (kt >= 2 * qt) {
        const int kb = kt * 64;
#pragma unroll
        for (int nf = 0; nf < 4; ++nf)
#pragma unroll
          for (int r = 0; r < 4; ++r) {
            float v = s[nf][r] * qscale;
            if (kb + nf * 16 + lg * 4 + r > qrow) v = -1.0e30f;
            s[nf][r] = v;
          }
      } else {
#pragma unroll
        for (int nf = 0; nf < 4; ++nf)
#pragma unroll
          for (int r = 0; r < 4; ++r) s[nf][r] *= qscale;
      }

      float t0a = fmaxf(fmaxf(s[0][0], s[0][1]), fmaxf(s[0][2], s[0][3]));
      float t1a = fmaxf(fmaxf(s[1][0], s[1][1]), fmaxf(s[1][2], s[1][3]));
      float t2a = fmaxf(fmaxf(s[2][0], s[2][1]), fmaxf(s[2][2], s[2][3]));
      float t3a = fmaxf(fmaxf(s[3][0], s[3][1]), fmaxf(s[3][2], s[3][3]));
      float pmax = fmaxf(fmaxf(t0a, t1a), fmaxf(t2a, t3a));
      pmax = fmaxf(pmax, __shfl_xor(pmax, 16));
      pmax = fmaxf(pmax, __shfl_xor(pmax, 32));

      if (!__all(pmax <= m)) {
        const float mnew = fmaxf(m, pmax);
        const float fct = __builtin_amdgcn_exp2f(m - mnew);
        m = mnew;
        l *= fct;
#pragma unroll
        for (int r = 0; r < 4; ++r) {
          const float fr = __shfl(fct, lg * 4 + r);
#pragma unroll
          for (int nf = 0; nf < 4; ++nf) o_acc[nf][r] *= fr;
        }
      }

      float p[4][4];
#pragma unroll
      for (int nf = 0; nf < 4; ++nf)
#pragma unroll
        for (int r = 0; r < 4; ++r) p[nf][r] = __builtin_amdgcn_exp2f(s[nf][r] - m);
      float s0a = (p[0][0] + p[0][1]) + (p[0][2] + p[0][3]);
      float s1a = (p[1][0] + p[1][1]) + (p[1][2] + p[1][3]);
      float s2a = (p[2][0] + p[2][1]) + (p[2][2] + p[2][3]);
      float s3a = (p[3][0] + p[3][1]) + (p[3][2] + p[3][3]);
      float psum = (s0a + s1a) + (s2a + s3a);
      psum += __shfl_xor(psum, 16);
      psum += __shfl_xor(psum, 32);
      l += psum;

      // P -> per-wave LDS region (packed b64, swizzled); same-wave RAW
#pragma unroll
      for (int nf = 0; nf < 4; ++nf) {
        u16x4 pk;
        pk[0] = f2bf(p[nf][0]); pk[1] = f2bf(p[nf][1]);
        pk[2] = f2bf(p[nf][2]); pk[3] = f2bf(p[nf][3]);
        *(u16x4*)(lPb + l15 * 128 + ((nf * 32 + lg * 8) ^ ((l15 & 7) << 4))) = pk;
      }

      // O += P V
      __builtin_amdgcn_s_setprio(1);
#pragma unroll
      for (int sj = 0; sj < 2; ++sj) {
        bf16x8 ap = *(const bf16x8*)(lPb + l15 * 128 + ((sj * 64 + lg * 16) ^ ((l15 & 7) << 4)));
#pragma unroll
        for (int nf = 0; nf < 4; ++nf) {
          const int d = nf * 16 + l15;
          bf16x8 bv = *(const bf16x8*)&Vc[(d * 128 + ((sj * 64 + lg * 16) ^ ((d & 7) << 4))) >> 1];
          o_acc[nf] = __builtin_amdgcn_mfma_f32_16x16x32_bf16(ap, bv, o_acc[nf], 0, 0, 0);
        }
      }
      __builtin_amdgcn_s_setprio(0);
    }

    // epilogue: l-normalized bf16 partial O + (m,l)
    u16* pob = po + (size_t)hf * (4096ull * 1024ull);
#pragma unroll
    for (int r = 0; r < 4; ++r) {
      const float lv = __shfl(l, lg * 4 + r);
      const float li = (lv > 0.f) ? __builtin_amdgcn_rcpf(lv) : 0.f;
      const int row = q0 + w * 16 + lg * 4 + r;
#pragma unroll
      for (int nf = 0; nf < 4; ++nf) {
        const int col = h * 64 + nf * 16 + l15;
        pob[((size_t)b * T + row) * C + col] = f2bf(o_acc[nf][r] * li);
      }
    }
    if (lg == 0) {
      const size_t idx = (size_t)(b * T + qrow) * 16 + h;
      float* mp = mlf + (size_t)hf * 131072ull + idx * 2;
      mp[0] = m;
      mp[1] = l;
    }
  }
}

// ---------------- merge the two kv-halves: y = w1*o1 + w2*o2 ----------------
__global__ __launch_bounds__(256) void merge_o(const u16* __restrict__ po,
                                               const float* __restrict__ mlf,
                                               u16* __restrict__ y) {
  const int gid = blockIdx.x * 256 + threadIdx.x;   // 524288 threads
  const int row = gid >> 3, d0 = (gid & 7) * 8;     // row in [0, 65536)
  const int bt = row >> 4, h = row & 15;
  const float m1 = mlf[row * 2], l1 = mlf[row * 2 + 1];
  const float m2 = mlf[131072 + row * 2], l2 = mlf[131072 + row * 2 + 1];
  const float ms = fmaxf(m1, m2);
  const float a1 = l1 * __builtin_amdgcn_exp2f(m1 - ms);
  const float a2 = l2 * __builtin_amdgcn_exp2f(m2 - ms);
  const float inv = __builtin_amdgcn_rcpf(a1 + a2);
  const float w1 = a1 * inv, w2 = a2 * inv;
  const size_t off = (size_t)bt * 1024 + h * 64 + d0;
  u16x8 p1 = *(const u16x8*)&po[off];
  u16x8 p2 = *(const u16x8*)&po[4194304ull + off];
  u16x8 o;
#pragma unroll
  for (int j = 0; j < 8; ++j) o[j] = f2bf(w1 * bf2f(p1[j]) + w2 * bf2f(p2[j]));
  *(u16x8*)&y[off] = o;
}

extern "C" void kernel_launch(void* const* d_in, const int* in_sizes, int n_in,
                              void* d_out, int out_size, void* d_ws, size_t ws_size,
                              hipStream_t stream) {
  const float* x = (const float*)d_in[0];
  const float* Wqkv = (const float*)d_in[1];
  const float* Wproj = (const float*)d_in[2];
  float* out = (float*)d_out;

  constexpr int B = 2, T = 2048, C = 1024, C3 = 3072, H = 16, D = 64;
  constexpr int M = B * T;  // 4096

  u16* xb = (u16*)d_ws;                       // M*C
  u16* wqkvb = xb + (size_t)M * C;            // C3*C
  u16* wprojb = wqkvb + (size_t)C3 * C;       // C*C
  u16* qkvb = wprojb + (size_t)C * C;         // M*C3 (v-part unused)
  u16* vtb = qkvb + (size_t)M * C3;           // B*H*D*T = M*C
  u16* yb = vtb + (size_t)M * C;              // M*C
  u16* po = yb + (size_t)M * C;               // 2 * M*C (both halves)
  float* mlf = (float*)(po + 2ull * M * C);   // 2 * 65536 * 2 floats

  constexpr int n1 = (M * C) / 4, n2 = (C3 * C) / 4, n3 = (C * C) / 4;
  cvt3_f32_bf16<<<dim3((n1 + n2 + n3 + 255) / 256), 256, 0, stream>>>(
      x, Wqkv, Wproj, xb, n1, n2, n3);

  gemm_nt<1, 1><<<dim3((C3 / 128) * (M / 128)), 256, 0, stream>>>(
      xb, wqkvb, qkvb, vtb, M, C3, C, M / 128);
  attn_fwd<<<dim3(512), 512, 0, stream>>>(qkvb, vtb, po, mlf);
  merge_o<<<dim3(2048), 256, 0, stream>>>(po, mlf, yb);
  gemm_nt<0, 0><<<dim3((C / 128) * (M / 128)), 256, 0, stream>>>(
      yb, wprojb, out, nullptr, M, C, C, M / 128);
}